// Round 2
// baseline (1070.534 us; speedup 1.0000x reference)
//
#include <hip/hip_runtime.h>
#include <math.h>

// Problem constants
#define BATCH   8
#define QLEN    256
#define KLEN    2048
#define KDIM    512
#define ADIMC   512
#define NHEADS  4
#define DKH     128     // ADIM / NHEADS
#define CHUNKW  4

static constexpr float INV_SCALE = 0.04419417382415922f; // 1/sqrt(512)
static constexpr float EPSV = 1e-6f;

// ---------------------------------------------------------------------------
// Projection GEMM: C[M,N] = A[M,K] @ W[K,N] + bias[N]
// BM=BN=64, BK=16, 256 threads, 4x4 per thread.
// ---------------------------------------------------------------------------
__global__ __launch_bounds__(256) void proj_gemm(
    const float* __restrict__ A, const float* __restrict__ W,
    const float* __restrict__ bias, float* __restrict__ C,
    int M, int K, int N)
{
    __shared__ float As[16][65];
    __shared__ float Ws[16][65];
    const int tid = threadIdx.x;
    const int bm = blockIdx.y * 64, bn = blockIdx.x * 64;
    const int lr = tid >> 2, lc = (tid & 3) * 4;      // A-tile load: row, k-col
    const int wr = tid >> 4, wc = (tid & 15) * 4;     // W-tile load: k-row, n-col
    const int tm = (tid >> 4) * 4, tn = (tid & 15) * 4;
    float acc[4][4] = {};

    for (int k0 = 0; k0 < K; k0 += 16) {
        float4 av = *(const float4*)(A + (size_t)(bm + lr) * K + k0 + lc);
        float4 wv = *(const float4*)(W + (size_t)(k0 + wr) * N + bn + wc);
        As[lc + 0][lr] = av.x; As[lc + 1][lr] = av.y;
        As[lc + 2][lr] = av.z; As[lc + 3][lr] = av.w;
        Ws[wr][wc + 0] = wv.x; Ws[wr][wc + 1] = wv.y;
        Ws[wr][wc + 2] = wv.z; Ws[wr][wc + 3] = wv.w;
        __syncthreads();
        #pragma unroll
        for (int kk = 0; kk < 16; ++kk) {
            float a0 = As[kk][tm + 0], a1 = As[kk][tm + 1];
            float a2 = As[kk][tm + 2], a3 = As[kk][tm + 3];
            float b0 = Ws[kk][tn + 0], b1 = Ws[kk][tn + 1];
            float b2 = Ws[kk][tn + 2], b3 = Ws[kk][tn + 3];
            acc[0][0] += a0 * b0; acc[0][1] += a0 * b1; acc[0][2] += a0 * b2; acc[0][3] += a0 * b3;
            acc[1][0] += a1 * b0; acc[1][1] += a1 * b1; acc[1][2] += a1 * b2; acc[1][3] += a1 * b3;
            acc[2][0] += a2 * b0; acc[2][1] += a2 * b1; acc[2][2] += a2 * b2; acc[2][3] += a2 * b3;
            acc[3][0] += a3 * b0; acc[3][1] += a3 * b1; acc[3][2] += a3 * b2; acc[3][3] += a3 * b3;
        }
        __syncthreads();
    }
    const float c0 = bias[bn + tn + 0], c1 = bias[bn + tn + 1];
    const float c2 = bias[bn + tn + 2], c3 = bias[bn + tn + 3];
    #pragma unroll
    for (int i = 0; i < 4; ++i) {
        float4 o;
        o.x = acc[i][0] + c0; o.y = acc[i][1] + c1;
        o.z = acc[i][2] + c2; o.w = acc[i][3] + c3;
        *(float4*)(C + (size_t)(bm + tm + i) * N + bn + tn) = o;
    }
}

// ---------------------------------------------------------------------------
// Batched NT GEMM -> p_choose: per batch b,
//   e[q,k] = (q_m[b,q,:] . k_m[b,k,:]) * INV_SCALE + r
//   p      = sigmoid(e + noise[b,q,k])
// ---------------------------------------------------------------------------
__global__ __launch_bounds__(256) void pchoose_gemm(
    const float* __restrict__ qm, const float* __restrict__ km,
    const float* __restrict__ noise, const float* __restrict__ rp,
    float* __restrict__ p)
{
    const int b = blockIdx.z;
    const float* A = qm + (size_t)b * QLEN * ADIMC;
    const float* B = km + (size_t)b * KLEN * ADIMC;
    __shared__ float As[16][65];
    __shared__ float Bs[16][65];
    const int tid = threadIdx.x;
    const int bm = blockIdx.y * 64, bn = blockIdx.x * 64;   // bm: q, bn: k
    const int lr = tid >> 2, lc = (tid & 3) * 4;
    const int tm = (tid >> 4) * 4, tn = (tid & 15) * 4;
    float acc[4][4] = {};

    for (int k0 = 0; k0 < ADIMC; k0 += 16) {
        float4 av = *(const float4*)(A + (size_t)(bm + lr) * ADIMC + k0 + lc);
        float4 bv = *(const float4*)(B + (size_t)(bn + lr) * ADIMC + k0 + lc);
        As[lc + 0][lr] = av.x; As[lc + 1][lr] = av.y;
        As[lc + 2][lr] = av.z; As[lc + 3][lr] = av.w;
        Bs[lc + 0][lr] = bv.x; Bs[lc + 1][lr] = bv.y;
        Bs[lc + 2][lr] = bv.z; Bs[lc + 3][lr] = bv.w;
        __syncthreads();
        #pragma unroll
        for (int kk = 0; kk < 16; ++kk) {
            float a0 = As[kk][tm + 0], a1 = As[kk][tm + 1];
            float a2 = As[kk][tm + 2], a3 = As[kk][tm + 3];
            float b0 = Bs[kk][tn + 0], b1 = Bs[kk][tn + 1];
            float b2 = Bs[kk][tn + 2], b3 = Bs[kk][tn + 3];
            acc[0][0] += a0 * b0; acc[0][1] += a0 * b1; acc[0][2] += a0 * b2; acc[0][3] += a0 * b3;
            acc[1][0] += a1 * b0; acc[1][1] += a1 * b1; acc[1][2] += a1 * b2; acc[1][3] += a1 * b3;
            acc[2][0] += a2 * b0; acc[2][1] += a2 * b1; acc[2][2] += a2 * b2; acc[2][3] += a2 * b3;
            acc[3][0] += a3 * b0; acc[3][1] += a3 * b1; acc[3][2] += a3 * b2; acc[3][3] += a3 * b3;
        }
        __syncthreads();
    }
    const float rv = rp[0];
    #pragma unroll
    for (int i = 0; i < 4; ++i) {
        const int q = bm + tm + i;
        const size_t rowoff = ((size_t)b * QLEN + q) * KLEN;
        #pragma unroll
        for (int j = 0; j < 4; ++j) {
            const int k = bn + tn + j;
            float e = acc[i][j] * INV_SCALE + rv + noise[rowoff + k];
            p[rowoff + k] = 1.0f / (1.0f + expf(-e));
        }
    }
}

// ---------------------------------------------------------------------------
// Batched NT GEMM -> e_chunk: per (b,h),
//   e[q,k] = (q_c[b,q,h,:] . k_c[b,k,h,:]) * INV_SCALE   -> out[b,h,q,k]
// ---------------------------------------------------------------------------
__global__ __launch_bounds__(256) void echunk_gemm(
    const float* __restrict__ qc, const float* __restrict__ kc,
    float* __restrict__ out)
{
    const int z = blockIdx.z;
    const int b = z >> 2, h = z & 3;
    const float* A = qc + (size_t)b * QLEN * ADIMC + h * DKH;
    const float* B = kc + (size_t)b * KLEN * ADIMC + h * DKH;
    __shared__ float As[16][65];
    __shared__ float Bs[16][65];
    const int tid = threadIdx.x;
    const int bm = blockIdx.y * 64, bn = blockIdx.x * 64;
    const int lr = tid >> 2, lc = (tid & 3) * 4;
    const int tm = (tid >> 4) * 4, tn = (tid & 15) * 4;
    float acc[4][4] = {};

    for (int k0 = 0; k0 < DKH; k0 += 16) {
        float4 av = *(const float4*)(A + (size_t)(bm + lr) * ADIMC + k0 + lc);
        float4 bv = *(const float4*)(B + (size_t)(bn + lr) * ADIMC + k0 + lc);
        As[lc + 0][lr] = av.x; As[lc + 1][lr] = av.y;
        As[lc + 2][lr] = av.z; As[lc + 3][lr] = av.w;
        Bs[lc + 0][lr] = bv.x; Bs[lc + 1][lr] = bv.y;
        Bs[lc + 2][lr] = bv.z; Bs[lc + 3][lr] = bv.w;
        __syncthreads();
        #pragma unroll
        for (int kk = 0; kk < 16; ++kk) {
            float a0 = As[kk][tm + 0], a1 = As[kk][tm + 1];
            float a2 = As[kk][tm + 2], a3 = As[kk][tm + 3];
            float b0 = Bs[kk][tn + 0], b1 = Bs[kk][tn + 1];
            float b2 = Bs[kk][tn + 2], b3 = Bs[kk][tn + 3];
            acc[0][0] += a0 * b0; acc[0][1] += a0 * b1; acc[0][2] += a0 * b2; acc[0][3] += a0 * b3;
            acc[1][0] += a1 * b0; acc[1][1] += a1 * b1; acc[1][2] += a1 * b2; acc[1][3] += a1 * b3;
            acc[2][0] += a2 * b0; acc[2][1] += a2 * b1; acc[2][2] += a2 * b2; acc[2][3] += a2 * b3;
            acc[3][0] += a3 * b0; acc[3][1] += a3 * b1; acc[3][2] += a3 * b2; acc[3][3] += a3 * b3;
        }
        __syncthreads();
    }
    #pragma unroll
    for (int i = 0; i < 4; ++i) {
        const int q = bm + tm + i;
        const size_t rowoff = (((size_t)b * NHEADS + h) * QLEN + q) * KLEN;
        float4 o;
        o.x = acc[i][0] * INV_SCALE; o.y = acc[i][1] * INV_SCALE;
        o.z = acc[i][2] * INV_SCALE; o.w = acc[i][3] * INV_SCALE;
        *(float4*)(out + rowoff + bn + tn) = o;
    }
}

// ---------------------------------------------------------------------------
// cumprod_1mp: per (b,q) row of 2048:
//   cp[k] = exp(exclusive_cumsum(log(clip(1-p,1e-6,1)))[k])
// ---------------------------------------------------------------------------
__global__ __launch_bounds__(256) void cumprod_kernel(
    const float* __restrict__ p, float* __restrict__ cp)
{
    const size_t row = blockIdx.x;
    const float* pr = p + row * KLEN;
    float* cr = cp + row * KLEN;
    const int tid = threadIdx.x;
    const int lane = tid & 63, wid = tid >> 6;
    __shared__ float waveTot[4];

    float4 v0 = *(const float4*)(pr + tid * 8);
    float4 v1 = *(const float4*)(pr + tid * 8 + 4);
    float pv[8] = {v0.x, v0.y, v0.z, v0.w, v1.x, v1.y, v1.z, v1.w};
    float excl[8];
    float run = 0.0f;
    #pragma unroll
    for (int j = 0; j < 8; ++j) {
        float l = logf(fminf(fmaxf(1.0f - pv[j], EPSV), 1.0f));
        excl[j] = run;
        run += l;
    }
    float s = run;
    #pragma unroll
    for (int off = 1; off < 64; off <<= 1) {
        float v = __shfl_up(s, off);
        if (lane >= off) s += v;
    }
    if (lane == 63) waveTot[wid] = s;
    __syncthreads();
    float wex = 0.0f;
    for (int w = 0; w < wid; ++w) wex += waveTot[w];
    const float texcl = wex + s - run;

    float4 o0, o1;
    o0.x = expf(texcl + excl[0]); o0.y = expf(texcl + excl[1]);
    o0.z = expf(texcl + excl[2]); o0.w = expf(texcl + excl[3]);
    o1.x = expf(texcl + excl[4]); o1.y = expf(texcl + excl[5]);
    o1.z = expf(texcl + excl[6]); o1.w = expf(texcl + excl[7]);
    *(float4*)(cr + tid * 8) = o0;
    *(float4*)(cr + tid * 8 + 4) = o1;
}

// ---------------------------------------------------------------------------
// alpha recurrence: ONE WAVE (64 threads) per batch, 32 elems/thread.
// No barriers, no LDS. Per q-step:
//   pass1: in-register inclusive prefix of t_j = aw_j * rcp_j  (31 serial adds)
//   wave exclusive scan of per-lane totals (6 shfl_up)
//   pass2: aw_j = (p_j*cp_j) * (lane_excl + incl_j)  (independent FMAs)
// Next row's p*cp and rcp(clip(cp)) are prefetched one iteration ahead into
// the alternate register buffer (2x-unrolled loop ping-pong), so the critical
// path sees only multiplies. Alpha overwrites p in place.
// ---------------------------------------------------------------------------
__global__ __launch_bounds__(64) void alpha_kernel(
    float* __restrict__ p_alpha, const float* __restrict__ cp)
{
    const int b = blockIdx.x;
    const int t = threadIdx.x;   // 0..63
    float* prow = p_alpha + (size_t)b * QLEN * KLEN + t * 32;
    const float* crow = cp + (size_t)b * QLEN * KLEN + t * 32;

    float aw[32];
    #pragma unroll
    for (int j = 0; j < 32; ++j) aw[j] = 0.0f;
    if (t == 0) aw[0] = 1.0f;

    float mA[32], rA[32], mB[32], rB[32];
    #pragma unroll
    for (int v = 0; v < 8; ++v) {
        float4 pv = *(const float4*)(prow + v * 4);
        float4 cv = *(const float4*)(crow + v * 4);
        mA[v*4+0] = pv.x * cv.x; rA[v*4+0] = __builtin_amdgcn_rcpf(fminf(fmaxf(cv.x, EPSV), 1.0f));
        mA[v*4+1] = pv.y * cv.y; rA[v*4+1] = __builtin_amdgcn_rcpf(fminf(fmaxf(cv.y, EPSV), 1.0f));
        mA[v*4+2] = pv.z * cv.z; rA[v*4+2] = __builtin_amdgcn_rcpf(fminf(fmaxf(cv.z, EPSV), 1.0f));
        mA[v*4+3] = pv.w * cv.w; rA[v*4+3] = __builtin_amdgcn_rcpf(fminf(fmaxf(cv.w, EPSV), 1.0f));
    }

#define ALPHA_STEP(I, MC, RC, MN, RN)                                          \
    {                                                                          \
        const int i_ = (I);                                                    \
        if (i_ + 1 < QLEN) {  /* prefetch row i+1, off critical path */        \
            const float* pn = prow + (size_t)(i_ + 1) * KLEN;                  \
            const float* cn = crow + (size_t)(i_ + 1) * KLEN;                  \
            _Pragma("unroll")                                                  \
            for (int v = 0; v < 8; ++v) {                                      \
                float4 pv = *(const float4*)(pn + v * 4);                      \
                float4 cv = *(const float4*)(cn + v * 4);                      \
                MN[v*4+0] = pv.x * cv.x; RN[v*4+0] = __builtin_amdgcn_rcpf(fminf(fmaxf(cv.x, EPSV), 1.0f)); \
                MN[v*4+1] = pv.y * cv.y; RN[v*4+1] = __builtin_amdgcn_rcpf(fminf(fmaxf(cv.y, EPSV), 1.0f)); \
                MN[v*4+2] = pv.z * cv.z; RN[v*4+2] = __builtin_amdgcn_rcpf(fminf(fmaxf(cv.z, EPSV), 1.0f)); \
                MN[v*4+3] = pv.w * cv.w; RN[v*4+3] = __builtin_amdgcn_rcpf(fminf(fmaxf(cv.w, EPSV), 1.0f)); \
            }                                                                  \
        }                                                                      \
        float incl[32];                                                        \
        float run = 0.0f;                                                      \
        _Pragma("unroll")                                                      \
        for (int j = 0; j < 32; ++j) { run += aw[j] * RC[j]; incl[j] = run; }  \
        float s_ = run;                                                        \
        _Pragma("unroll")                                                      \
        for (int off = 1; off < 64; off <<= 1) {                               \
            float v_ = __shfl_up(s_, off);                                     \
            if (t >= off) s_ += v_;                                            \
        }                                                                      \
        const float excl = s_ - run;                                           \
        _Pragma("unroll")                                                      \
        for (int j = 0; j < 32; ++j) aw[j] = MC[j] * (excl + incl[j]);         \
        float* orow = prow + (size_t)i_ * KLEN;                                \
        _Pragma("unroll")                                                      \
        for (int v = 0; v < 8; ++v) {                                          \
            float4 o;                                                          \
            o.x = aw[v*4+0]; o.y = aw[v*4+1]; o.z = aw[v*4+2]; o.w = aw[v*4+3];\
            *(float4*)(orow + v * 4) = o;                                      \
        }                                                                      \
    }

    for (int i0 = 0; i0 < QLEN; i0 += 2) {
        ALPHA_STEP(i0,     mA, rA, mB, rB)
        ALPHA_STEP(i0 + 1, mB, rB, mA, rA)
    }
#undef ALPHA_STEP
}

// ---------------------------------------------------------------------------
// beta: per (b,h,q) row of 2048 (e_chunk already in d_out, overwritten)
// ---------------------------------------------------------------------------
__global__ __launch_bounds__(256) void beta_kernel(
    float* __restrict__ eo, const float* __restrict__ alpha)
{
    __shared__ float sse[KLEN + 3];
    __shared__ float su[KLEN + 3];
    __shared__ float wmax[4];

    const int tid = threadIdx.x;
    const int lane = tid & 63, wid = tid >> 6;
    const int row = blockIdx.x;                 // [B*H*Q]
    const int q = row & (QLEN - 1);
    const int b = row >> 10;
    float* erow = eo + (size_t)row * KLEN;
    const float* arow = alpha + ((size_t)b * QLEN + q) * KLEN;

    if (tid < 3) { sse[tid] = 0.0f; su[KLEN + tid] = 0.0f; }

    float ev[8];
    float lm = -INFINITY;
    #pragma unroll
    for (int j = 0; j < 8; ++j) {
        const int k = tid + 256 * j;
        ev[j] = erow[k];
        lm = fmaxf(lm, ev[j]);
    }
    #pragma unroll
    for (int off = 32; off > 0; off >>= 1) lm = fmaxf(lm, __shfl_xor(lm, off));
    if (lane == 0) wmax[wid] = lm;
    __syncthreads();
    const float mx = fmaxf(fmaxf(wmax[0], wmax[1]), fmaxf(wmax[2], wmax[3]));

    #pragma unroll
    for (int j = 0; j < 8; ++j) {
        const int k = tid + 256 * j;
        sse[k + 3] = fmaxf(expf(ev[j] - mx), 1e-5f);
    }
    __syncthreads();

    #pragma unroll
    for (int j = 0; j < 8; ++j) {
        const int k = tid + 256 * j;
        const float denom = sse[k + 3] + sse[k + 2] + sse[k + 1] + sse[k];
        su[k] = arow[k] / denom;
    }
    __syncthreads();

    #pragma unroll
    for (int j = 0; j < 8; ++j) {
        const int k = tid + 256 * j;
        erow[k] = sse[k + 3] * (su[k] + su[k + 1] + su[k + 2] + su[k + 3]);
    }
}

// ---------------------------------------------------------------------------
extern "C" void kernel_launch(void* const* d_in, const int* in_sizes, int n_in,
                              void* d_out, int out_size, void* d_ws, size_t ws_size,
                              hipStream_t stream)
{
    (void)in_sizes; (void)n_in; (void)out_size; (void)ws_size;
    const float* key_enc = (const float*)d_in[0];   // [8,2048,512]
    const float* query   = (const float*)d_in[1];   // [8,256,512]
    const float* noise   = (const float*)d_in[2];   // [8,256,2048]
    const float* Wk_m    = (const float*)d_in[3];
    const float* bk_m    = (const float*)d_in[4];
    const float* Wq_m    = (const float*)d_in[5];
    const float* bq_m    = (const float*)d_in[6];
    const float* rp      = (const float*)d_in[7];
    const float* Wk_c    = (const float*)d_in[8];
    const float* bk_c    = (const float*)d_in[9];
    const float* Wq_c    = (const float*)d_in[10];
    const float* bq_c    = (const float*)d_in[11];
    float* out = (float*)d_out;                     // [8,4,256,2048]

    // workspace layout (floats)
    float* ws = (float*)d_ws;
    float* k_m     = ws;                                   // 8*2048*512
    float* k_c     = k_m + (size_t)BATCH * KLEN * ADIMC;   // 8*2048*512
    float* q_m     = k_c + (size_t)BATCH * KLEN * ADIMC;   // 8*256*512
    float* q_c     = q_m + (size_t)BATCH * QLEN * ADIMC;   // 8*256*512
    float* p_alpha = q_c + (size_t)BATCH * QLEN * ADIMC;   // 8*256*2048 (p, then alpha)
    float* cp      = p_alpha + (size_t)BATCH * QLEN * KLEN;// 8*256*2048

    // 1) projections
    {
        dim3 blk(256);
        dim3 gk(ADIMC / 64, (BATCH * KLEN) / 64);   // (8, 256)
        dim3 gq(ADIMC / 64, (BATCH * QLEN) / 64);   // (8, 32)
        hipLaunchKernelGGL(proj_gemm, gk, blk, 0, stream,
                           key_enc, Wk_m, bk_m, k_m, BATCH * KLEN, KDIM, ADIMC);
        hipLaunchKernelGGL(proj_gemm, gk, blk, 0, stream,
                           key_enc, Wk_c, bk_c, k_c, BATCH * KLEN, KDIM, ADIMC);
        hipLaunchKernelGGL(proj_gemm, gq, blk, 0, stream,
                           query, Wq_m, bq_m, q_m, BATCH * QLEN, KDIM, ADIMC);
        hipLaunchKernelGGL(proj_gemm, gq, blk, 0, stream,
                           query, Wq_c, bq_c, q_c, BATCH * QLEN, KDIM, ADIMC);
    }
    // 2) e_mono -> p_choose
    hipLaunchKernelGGL(pchoose_gemm, dim3(KLEN / 64, QLEN / 64, BATCH), dim3(256), 0, stream,
                       q_m, k_m, noise, rp, p_alpha);
    // 3) cumprod
    hipLaunchKernelGGL(cumprod_kernel, dim3(BATCH * QLEN), dim3(256), 0, stream,
                       p_alpha, cp);
    // 4) alpha recurrence (in-place over p) — 1 wave per batch
    hipLaunchKernelGGL(alpha_kernel, dim3(BATCH), dim3(64), 0, stream,
                       p_alpha, cp);
    // 5) e_chunk into d_out
    hipLaunchKernelGGL(echunk_gemm, dim3(KLEN / 64, QLEN / 64, BATCH * NHEADS), dim3(256), 0, stream,
                       q_c, k_c, out);
    // 6) beta (overwrites e_chunk rows in d_out)
    hipLaunchKernelGGL(beta_kernel, dim3(BATCH * NHEADS * QLEN), dim3(256), 0, stream,
                       out, p_alpha);
}

// Round 3
// 542.403 us; speedup vs baseline: 1.9737x; 1.9737x over previous
//
#include <hip/hip_runtime.h>
#include <math.h>

// Problem constants
#define BATCH   8
#define QLEN    256
#define KLEN    2048
#define KDIM    512
#define ADIMC   512
#define NHEADS  4
#define DKH     128
#define CHUNKW  4

static constexpr float INV_SCALE = 0.04419417382415922f; // 1/sqrt(512)
static constexpr float EPSV = 1e-6f;

typedef __attribute__((ext_vector_type(8))) short bf16x8;
typedef __attribute__((ext_vector_type(4))) float f32x4;

__device__ __forceinline__ unsigned short f2bf(float f) {
    unsigned u = __builtin_bit_cast(unsigned, f);
    u += 0x7fffu + ((u >> 16) & 1u);   // round-to-nearest-even
    return (unsigned short)(u >> 16);
}

// ---------------------------------------------------------------------------
// Elementwise f32 -> bf16 cast (4 elems/thread)
// ---------------------------------------------------------------------------
__global__ __launch_bounds__(256) void cast_bf16(
    const float* __restrict__ x, unsigned short* __restrict__ y, int n4)
{
    int i = blockIdx.x * 256 + threadIdx.x;
    if (i < n4) {
        float4 v = ((const float4*)x)[i];
        ushort4 o;
        o.x = f2bf(v.x); o.y = f2bf(v.y); o.z = f2bf(v.z); o.w = f2bf(v.w);
        ((ushort4*)y)[i] = o;
    }
}

// ---------------------------------------------------------------------------
// Transpose-cast: W [512 x 512] (k-major rows) -> WT [512 x 512] bf16, WT[n][k]
// ---------------------------------------------------------------------------
__global__ __launch_bounds__(256) void transpose_cast(
    const float* __restrict__ W, unsigned short* __restrict__ WT)
{
    __shared__ float tile[32][33];
    const int tx = threadIdx.x;          // 0..31
    const int ty = threadIdx.y;          // 0..7
    const int k0 = blockIdx.y * 32, n0 = blockIdx.x * 32;
    #pragma unroll
    for (int i = 0; i < 32; i += 8)
        tile[ty + i][tx] = W[(size_t)(k0 + ty + i) * KDIM + n0 + tx];
    __syncthreads();
    #pragma unroll
    for (int i = 0; i < 32; i += 8)
        WT[(size_t)(n0 + ty + i) * KDIM + k0 + tx] = f2bf(tile[tx][ty + i]);
}

// ---------------------------------------------------------------------------
// Generic NT MFMA core: wave computes 64x64 f32 tile of A[M,K] @ B[N,K]^T.
// A,B bf16, K-contiguous, 16B-aligned rows. Fragments loaded direct from
// global (L2-resident reuse; no LDS).
// 16x16x32 layout: A lane holds A[m=lane&15][k=quad*8+j]; B symmetric;
// C/D: col=lane&15, row=quad*4+reg.
// ---------------------------------------------------------------------------
template<int KSTEPS>
__device__ __forceinline__ void mfma_nt_core(
    const unsigned short* __restrict__ A, const unsigned short* __restrict__ B,
    int lda, int ldb, int m0, int n0, int lane, f32x4 acc[4][4])
{
    const int r = lane & 15, quad = lane >> 4;
    const unsigned short* ap = A + (size_t)(m0 + r) * lda + quad * 8;
    const unsigned short* bp = B + (size_t)(n0 + r) * ldb + quad * 8;
    #pragma unroll 4
    for (int ks = 0; ks < KSTEPS; ++ks) {
        bf16x8 af[4], bg[4];
        #pragma unroll
        for (int f = 0; f < 4; ++f)
            af[f] = *(const bf16x8*)(ap + (size_t)f * 16 * lda + ks * 32);
        #pragma unroll
        for (int f = 0; f < 4; ++f)
            bg[f] = *(const bf16x8*)(bp + (size_t)f * 16 * ldb + ks * 32);
        #pragma unroll
        for (int i = 0; i < 4; ++i)
            #pragma unroll
            for (int j = 0; j < 4; ++j)
                acc[i][j] = __builtin_amdgcn_mfma_f32_16x16x32_bf16(
                    af[i], bg[j], acc[i][j], 0, 0, 0);
    }
}

__device__ __forceinline__ void zero_acc(f32x4 acc[4][4]) {
    #pragma unroll
    for (int i = 0; i < 4; ++i)
        #pragma unroll
        for (int j = 0; j < 4; ++j)
            acc[i][j] = f32x4{0.f, 0.f, 0.f, 0.f};
}

// ---------------------------------------------------------------------------
// Projection: C[M x 1024] bf16 = A[M x 512] @ WT[1024 x 512]^T + bias
// bias col n: n<512 -> bias_m[n], else bias_c[n-512]
// ---------------------------------------------------------------------------
__global__ __launch_bounds__(256) void proj_mfma(
    const unsigned short* __restrict__ A, const unsigned short* __restrict__ WT,
    const float* __restrict__ bias_m, const float* __restrict__ bias_c,
    unsigned short* __restrict__ C)
{
    const int wave = threadIdx.x >> 6, lane = threadIdx.x & 63;
    const int m0 = blockIdx.y * 128 + (wave >> 1) * 64;
    const int n0 = blockIdx.x * 128 + (wave & 1) * 64;
    f32x4 acc[4][4]; zero_acc(acc);
    mfma_nt_core<16>(A, WT, KDIM, KDIM, m0, n0, lane, acc);
    const int r = lane & 15, quad = lane >> 4;
    #pragma unroll
    for (int j = 0; j < 4; ++j) {
        const int n = n0 + j * 16 + r;
        const float bv = (n < 512) ? bias_m[n] : bias_c[n - 512];
        #pragma unroll
        for (int i = 0; i < 4; ++i) {
            #pragma unroll
            for (int reg = 0; reg < 4; ++reg) {
                const int m = m0 + i * 16 + quad * 4 + reg;
                C[(size_t)m * 1024 + n] = f2bf(acc[i][j][reg] + bv);
            }
        }
    }
}

// ---------------------------------------------------------------------------
// p_choose: per batch b, p = sigmoid(qm[b] @ km[b]^T / sqrt(512) + r + noise)
// qm/km are the first 512 cols of q_proj/k_proj (ld = 1024).
// ---------------------------------------------------------------------------
__global__ __launch_bounds__(256) void pchoose_mfma(
    const unsigned short* __restrict__ qp, const unsigned short* __restrict__ kp,
    const float* __restrict__ noise, const float* __restrict__ rp,
    float* __restrict__ p)
{
    const int b = blockIdx.z;
    const unsigned short* A = qp + (size_t)b * QLEN * 1024;
    const unsigned short* B = kp + (size_t)b * KLEN * 1024;
    const int wave = threadIdx.x >> 6, lane = threadIdx.x & 63;
    const int m0 = blockIdx.y * 128 + (wave >> 1) * 64;
    const int n0 = blockIdx.x * 128 + (wave & 1) * 64;
    f32x4 acc[4][4]; zero_acc(acc);
    mfma_nt_core<16>(A, B, 1024, 1024, m0, n0, lane, acc);
    const int r = lane & 15, quad = lane >> 4;
    const float rv = rp[0];
    #pragma unroll
    for (int i = 0; i < 4; ++i) {
        #pragma unroll
        for (int reg = 0; reg < 4; ++reg) {
            const int q = m0 + i * 16 + quad * 4 + reg;
            const size_t rowoff = ((size_t)b * QLEN + q) * KLEN;
            #pragma unroll
            for (int j = 0; j < 4; ++j) {
                const int k = n0 + j * 16 + r;
                const float e = acc[i][j][reg] * INV_SCALE + rv + noise[rowoff + k];
                p[rowoff + k] = 1.0f / (1.0f + expf(-e));
            }
        }
    }
}

// ---------------------------------------------------------------------------
// e_chunk: per (b,h), out[b,h,q,k] = qc_h[b] @ kc_h[b]^T / sqrt(512)
// head slice = cols [512 + h*128, +128) of q_proj/k_proj (ld = 1024), K=128.
// ---------------------------------------------------------------------------
__global__ __launch_bounds__(256) void echunk_mfma(
    const unsigned short* __restrict__ qp, const unsigned short* __restrict__ kp,
    float* __restrict__ out)
{
    const int z = blockIdx.z, b = z >> 2, h = z & 3;
    const unsigned short* A = qp + (size_t)b * QLEN * 1024 + 512 + h * DKH;
    const unsigned short* B = kp + (size_t)b * KLEN * 1024 + 512 + h * DKH;
    const int wave = threadIdx.x >> 6, lane = threadIdx.x & 63;
    const int m0 = blockIdx.y * 128 + (wave >> 1) * 64;
    const int n0 = blockIdx.x * 128 + (wave & 1) * 64;
    f32x4 acc[4][4]; zero_acc(acc);
    mfma_nt_core<4>(A, B, 1024, 1024, m0, n0, lane, acc);
    const int r = lane & 15, quad = lane >> 4;
    #pragma unroll
    for (int i = 0; i < 4; ++i) {
        #pragma unroll
        for (int reg = 0; reg < 4; ++reg) {
            const int q = m0 + i * 16 + quad * 4 + reg;
            const size_t rowoff = ((size_t)z * QLEN + q) * KLEN;
            #pragma unroll
            for (int j = 0; j < 4; ++j) {
                const int k = n0 + j * 16 + r;
                out[rowoff + k] = acc[i][j][reg] * INV_SCALE;
            }
        }
    }
}

// ---------------------------------------------------------------------------
// cumprod: per (b,q) row, cp = exp(exclusive_cumsum(log(clip(1-p,1e-6,1)))).
// Emits mArr = p*cp and rArr = 1/clip(cp,1e-6,1) so alpha_kernel is pure
// multiply-add on its critical path.
// ---------------------------------------------------------------------------
__global__ __launch_bounds__(256) void cumprod_kernel(
    const float* __restrict__ p, float* __restrict__ mArr, float* __restrict__ rArr)
{
    const size_t row = blockIdx.x;
    const float* pr = p + row * KLEN;
    float* mr = mArr + row * KLEN;
    float* rr = rArr + row * KLEN;
    const int tid = threadIdx.x;
    const int lane = tid & 63, wid = tid >> 6;
    __shared__ float waveTot[4];

    float4 v0 = *(const float4*)(pr + tid * 8);
    float4 v1 = *(const float4*)(pr + tid * 8 + 4);
    float pv[8] = {v0.x, v0.y, v0.z, v0.w, v1.x, v1.y, v1.z, v1.w};
    float excl[8];
    float run = 0.0f;
    #pragma unroll
    for (int j = 0; j < 8; ++j) {
        float l = logf(fminf(fmaxf(1.0f - pv[j], EPSV), 1.0f));
        excl[j] = run;
        run += l;
    }
    float s = run;
    #pragma unroll
    for (int off = 1; off < 64; off <<= 1) {
        float v = __shfl_up(s, off);
        if (lane >= off) s += v;
    }
    if (lane == 63) waveTot[wid] = s;
    __syncthreads();
    float wex = 0.0f;
    for (int w = 0; w < wid; ++w) wex += waveTot[w];
    const float texcl = wex + s - run;

    float mv[8], rv[8];
    #pragma unroll
    for (int j = 0; j < 8; ++j) {
        const float cpv = expf(texcl + excl[j]);
        mv[j] = pv[j] * cpv;
        rv[j] = __builtin_amdgcn_rcpf(fminf(fmaxf(cpv, EPSV), 1.0f));
    }
    *(float4*)(mr + tid * 8)     = *(float4*)&mv[0];
    *(float4*)(mr + tid * 8 + 4) = *(float4*)&mv[4];
    *(float4*)(rr + tid * 8)     = *(float4*)&rv[0];
    *(float4*)(rr + tid * 8 + 4) = *(float4*)&rv[4];
}

// ---------------------------------------------------------------------------
// 64-lane inclusive prefix sum via DPP (≈6 VALU ops, no LDS round-trips)
// ---------------------------------------------------------------------------
__device__ __forceinline__ float wave_incl_scan(float x)
{
#define DPP_ADD(ctrl, rmask, bctrl)                                            \
    { int _t = __builtin_amdgcn_update_dpp(0, __builtin_bit_cast(int, x),      \
                                           ctrl, rmask, 0xf, bctrl);           \
      x += __builtin_bit_cast(float, _t); }
    DPP_ADD(0x111, 0xf, true)   // row_shr:1
    DPP_ADD(0x112, 0xf, true)   // row_shr:2
    DPP_ADD(0x114, 0xf, true)   // row_shr:4
    DPP_ADD(0x118, 0xf, true)   // row_shr:8
    DPP_ADD(0x142, 0xa, false)  // row_bcast:15 -> rows 1,3
    DPP_ADD(0x143, 0xc, false)  // row_bcast:31 -> rows 2,3
#undef DPP_ADD
    return x;
}

// ---------------------------------------------------------------------------
// alpha recurrence: ONE WAVE per batch, 32 elems/lane, depth-4 register
// prefetch of (m,r) rows; DPP scan; zero divides/rcp on critical path.
// Writes alpha into the (dead) p buffer.
// ---------------------------------------------------------------------------
__global__ __launch_bounds__(64) void alpha_kernel(
    const float* __restrict__ mArr, const float* __restrict__ rArr,
    float* __restrict__ alpha)
{
    const int b = blockIdx.x;
    const int t = threadIdx.x;   // 0..63
    const float* mrow = mArr + (size_t)b * QLEN * KLEN + t * 32;
    const float* rrow = rArr + (size_t)b * QLEN * KLEN + t * 32;
    float* arow = alpha + (size_t)b * QLEN * KLEN + t * 32;

    float aw[32];
    #pragma unroll
    for (int j = 0; j < 32; ++j) aw[j] = 0.0f;
    if (t == 0) aw[0] = 1.0f;

    float bm[4][32], br[4][32];
    #pragma unroll
    for (int d = 0; d < 4; ++d) {
        #pragma unroll
        for (int v = 0; v < 8; ++v) {
            *(float4*)&bm[d][v * 4] = *(const float4*)(mrow + (size_t)d * KLEN + v * 4);
            *(float4*)&br[d][v * 4] = *(const float4*)(rrow + (size_t)d * KLEN + v * 4);
        }
    }

#define ALPHA_STEP(I, D)                                                       \
    {                                                                          \
        const int i_ = (I);                                                    \
        float incl[32];                                                        \
        float run = 0.0f;                                                      \
        _Pragma("unroll")                                                      \
        for (int j = 0; j < 32; ++j) { run = fmaf(aw[j], br[D][j], run); incl[j] = run; } \
        const float tot = wave_incl_scan(run);                                 \
        const float excl = tot - run;                                          \
        _Pragma("unroll")                                                      \
        for (int j = 0; j < 32; ++j) aw[j] = bm[D][j] * (excl + incl[j]);      \
        float* o_ = arow + (size_t)i_ * KLEN;                                  \
        _Pragma("unroll")                                                      \
        for (int v = 0; v < 8; ++v) {                                          \
            float4 ov; ov.x = aw[v*4+0]; ov.y = aw[v*4+1];                     \
            ov.z = aw[v*4+2]; ov.w = aw[v*4+3];                                \
            *(float4*)(o_ + v * 4) = ov;                                       \
        }                                                                      \
        if (i_ + 4 < QLEN) {                                                   \
            const float* mn_ = mrow + (size_t)(i_ + 4) * KLEN;                 \
            const float* rn_ = rrow + (size_t)(i_ + 4) * KLEN;                 \
            _Pragma("unroll")                                                  \
            for (int v = 0; v < 8; ++v) {                                      \
                *(float4*)&bm[D][v * 4] = *(const float4*)(mn_ + v * 4);       \
                *(float4*)&br[D][v * 4] = *(const float4*)(rn_ + v * 4);       \
            }                                                                  \
        }                                                                      \
    }

    for (int i0 = 0; i0 < QLEN; i0 += 4) {
        ALPHA_STEP(i0 + 0, 0)
        ALPHA_STEP(i0 + 1, 1)
        ALPHA_STEP(i0 + 2, 2)
        ALPHA_STEP(i0 + 3, 3)
    }
#undef ALPHA_STEP
}

// ---------------------------------------------------------------------------
// beta: per (b,h,q) row of 2048 (e_chunk in d_out, overwritten)
// ---------------------------------------------------------------------------
__global__ __launch_bounds__(256) void beta_kernel(
    float* __restrict__ eo, const float* __restrict__ alpha)
{
    __shared__ float sse[KLEN + 3];
    __shared__ float su[KLEN + 3];
    __shared__ float wmax[4];

    const int tid = threadIdx.x;
    const int lane = tid & 63, wid = tid >> 6;
    const int row = blockIdx.x;                 // [B*H*Q]
    const int q = row & (QLEN - 1);
    const int b = row >> 10;
    float* erow = eo + (size_t)row * KLEN;
    const float* arow = alpha + ((size_t)b * QLEN + q) * KLEN;

    if (tid < 3) { sse[tid] = 0.0f; su[KLEN + tid] = 0.0f; }

    float ev[8];
    float lm = -INFINITY;
    #pragma unroll
    for (int j = 0; j < 8; ++j) {
        const int k = tid + 256 * j;
        ev[j] = erow[k];
        lm = fmaxf(lm, ev[j]);
    }
    #pragma unroll
    for (int off = 32; off > 0; off >>= 1) lm = fmaxf(lm, __shfl_xor(lm, off));
    if (lane == 0) wmax[wid] = lm;
    __syncthreads();
    const float mx = fmaxf(fmaxf(wmax[0], wmax[1]), fmaxf(wmax[2], wmax[3]));

    #pragma unroll
    for (int j = 0; j < 8; ++j) {
        const int k = tid + 256 * j;
        sse[k + 3] = fmaxf(expf(ev[j] - mx), 1e-5f);
    }
    __syncthreads();

    #pragma unroll
    for (int j = 0; j < 8; ++j) {
        const int k = tid + 256 * j;
        const float denom = sse[k + 3] + sse[k + 2] + sse[k + 1] + sse[k];
        su[k] = arow[k] / denom;
    }
    __syncthreads();

    #pragma unroll
    for (int j = 0; j < 8; ++j) {
        const int k = tid + 256 * j;
        erow[k] = sse[k + 3] * (su[k] + su[k + 1] + su[k + 2] + su[k + 3]);
    }
}

// ---------------------------------------------------------------------------
extern "C" void kernel_launch(void* const* d_in, const int* in_sizes, int n_in,
                              void* d_out, int out_size, void* d_ws, size_t ws_size,
                              hipStream_t stream)
{
    (void)in_sizes; (void)n_in; (void)out_size; (void)ws_size;
    const float* key_enc = (const float*)d_in[0];   // [8,2048,512]
    const float* query   = (const float*)d_in[1];   // [8,256,512]
    const float* noise   = (const float*)d_in[2];   // [8,256,2048]
    const float* Wk_m    = (const float*)d_in[3];
    const float* bk_m    = (const float*)d_in[4];
    const float* Wq_m    = (const float*)d_in[5];
    const float* bq_m    = (const float*)d_in[6];
    const float* rp      = (const float*)d_in[7];
    const float* Wk_c    = (const float*)d_in[8];
    const float* bk_c    = (const float*)d_in[9];
    const float* Wq_c    = (const float*)d_in[10];
    const float* bq_c    = (const float*)d_in[11];
    float* out = (float*)d_out;                     // [8,4,256,2048]

    // workspace layout (bytes)
    char* w = (char*)d_ws;
    unsigned short* kx    = (unsigned short*)w; w += (size_t)BATCH * KLEN * KDIM * 2;   // 16.8 MB
    unsigned short* qx    = (unsigned short*)w; w += (size_t)BATCH * QLEN * KDIM * 2;   //  2.1 MB
    unsigned short* WTk   = (unsigned short*)w; w += (size_t)1024 * KDIM * 2;           //  1.0 MB
    unsigned short* WTq   = (unsigned short*)w; w += (size_t)1024 * KDIM * 2;           //  1.0 MB
    unsigned short* kproj = (unsigned short*)w; w += (size_t)BATCH * KLEN * 1024 * 2;   // 33.6 MB
    unsigned short* qproj = (unsigned short*)w; w += (size_t)BATCH * QLEN * 1024 * 2;   //  4.2 MB
    float* p_alpha = (float*)w; w += (size_t)BATCH * QLEN * KLEN * 4;                   // 16.8 MB
    float* mArr    = (float*)w; w += (size_t)BATCH * QLEN * KLEN * 4;                   // 16.8 MB
    float* rArr    = (float*)w;                                                         // 16.8 MB

    // 1) casts
    hipLaunchKernelGGL(cast_bf16, dim3(BATCH * KLEN * KDIM / 4 / 256), dim3(256), 0, stream,
                       key_enc, kx, BATCH * KLEN * KDIM / 4);
    hipLaunchKernelGGL(cast_bf16, dim3(BATCH * QLEN * KDIM / 4 / 256), dim3(256), 0, stream,
                       query, qx, BATCH * QLEN * KDIM / 4);
    hipLaunchKernelGGL(transpose_cast, dim3(16, 16), dim3(32, 8), 0, stream, Wk_m, WTk);
    hipLaunchKernelGGL(transpose_cast, dim3(16, 16), dim3(32, 8), 0, stream, Wk_c, WTk + (size_t)512 * KDIM);
    hipLaunchKernelGGL(transpose_cast, dim3(16, 16), dim3(32, 8), 0, stream, Wq_m, WTq);
    hipLaunchKernelGGL(transpose_cast, dim3(16, 16), dim3(32, 8), 0, stream, Wq_c, WTq + (size_t)512 * KDIM);

    // 2) projections (bf16 MFMA, fused bias, bf16 out)
    hipLaunchKernelGGL(proj_mfma, dim3(8, BATCH * KLEN / 128), dim3(256), 0, stream,
                       kx, WTk, bk_m, bk_c, kproj);
    hipLaunchKernelGGL(proj_mfma, dim3(8, BATCH * QLEN / 128), dim3(256), 0, stream,
                       qx, WTq, bq_m, bq_c, qproj);

    // 3) p_choose (bf16 MFMA + sigmoid epilogue)
    hipLaunchKernelGGL(pchoose_mfma, dim3(KLEN / 128, QLEN / 128, BATCH), dim3(256), 0, stream,
                       qproj, kproj, noise, rp, p_alpha);

    // 4) cumprod -> (m, r)
    hipLaunchKernelGGL(cumprod_kernel, dim3(BATCH * QLEN), dim3(256), 0, stream,
                       p_alpha, mArr, rArr);

    // 5) alpha recurrence (1 wave/batch, DPP scan, depth-4 prefetch)
    hipLaunchKernelGGL(alpha_kernel, dim3(BATCH), dim3(64), 0, stream,
                       mArr, rArr, p_alpha);

    // 6) e_chunk (bf16 MFMA) into d_out
    hipLaunchKernelGGL(echunk_mfma, dim3(KLEN / 128, QLEN / 128, BATCH * NHEADS), dim3(256), 0, stream,
                       qproj, kproj, out);

    // 7) beta (overwrites e_chunk rows in d_out)
    hipLaunchKernelGGL(beta_kernel, dim3(BATCH * NHEADS * QLEN), dim3(256), 0, stream,
                       out, p_alpha);
}

// Round 5
// 496.779 us; speedup vs baseline: 2.1550x; 1.0918x over previous
//
#include <hip/hip_runtime.h>
#include <math.h>

// Problem constants
#define BATCH   8
#define QLEN    256
#define KLEN    2048
#define KDIM    512
#define ADIMC   512
#define NHEADS  4
#define DKH     128
#define CHUNKW  4
#define ADEPTH  8       // alpha prefetch ring depth (rows)

static constexpr float INV_SCALE = 0.04419417382415922f; // 1/sqrt(512)
static constexpr float EPSV = 1e-6f;

typedef __attribute__((ext_vector_type(8))) short bf16x8;
typedef __attribute__((ext_vector_type(4))) float f32x4;

__device__ __forceinline__ unsigned short f2bf(float f) {
    unsigned u = __builtin_bit_cast(unsigned, f);
    u += 0x7fffu + ((u >> 16) & 1u);   // round-to-nearest-even
    return (unsigned short)(u >> 16);
}

// ---------------------------------------------------------------------------
// Elementwise f32 -> bf16 cast (4 elems/thread)
// ---------------------------------------------------------------------------
__global__ __launch_bounds__(256) void cast_bf16(
    const float* __restrict__ x, unsigned short* __restrict__ y, int n4)
{
    int i = blockIdx.x * 256 + threadIdx.x;
    if (i < n4) {
        float4 v = ((const float4*)x)[i];
        ushort4 o;
        o.x = f2bf(v.x); o.y = f2bf(v.y); o.z = f2bf(v.z); o.w = f2bf(v.w);
        ((ushort4*)y)[i] = o;
    }
}

// ---------------------------------------------------------------------------
// Transpose-cast: W [512 x 512] (k-major rows) -> WT [512 x 512] bf16, WT[n][k]
// ---------------------------------------------------------------------------
__global__ __launch_bounds__(256) void transpose_cast(
    const float* __restrict__ W, unsigned short* __restrict__ WT)
{
    __shared__ float tile[32][33];
    const int tx = threadIdx.x;          // 0..31
    const int ty = threadIdx.y;          // 0..7
    const int k0 = blockIdx.y * 32, n0 = blockIdx.x * 32;
    #pragma unroll
    for (int i = 0; i < 32; i += 8)
        tile[ty + i][tx] = W[(size_t)(k0 + ty + i) * KDIM + n0 + tx];
    __syncthreads();
    #pragma unroll
    for (int i = 0; i < 32; i += 8)
        WT[(size_t)(n0 + ty + i) * KDIM + k0 + tx] = f2bf(tile[tx][ty + i]);
}

// ---------------------------------------------------------------------------
// Generic NT MFMA core: wave computes 64x64 f32 tile of A[M,K] @ B[N,K]^T.
// ---------------------------------------------------------------------------
template<int KSTEPS>
__device__ __forceinline__ void mfma_nt_core(
    const unsigned short* __restrict__ A, const unsigned short* __restrict__ B,
    int lda, int ldb, int m0, int n0, int lane, f32x4 acc[4][4])
{
    const int r = lane & 15, quad = lane >> 4;
    const unsigned short* ap = A + (size_t)(m0 + r) * lda + quad * 8;
    const unsigned short* bp = B + (size_t)(n0 + r) * ldb + quad * 8;
    #pragma unroll 4
    for (int ks = 0; ks < KSTEPS; ++ks) {
        bf16x8 af[4], bg[4];
        #pragma unroll
        for (int f = 0; f < 4; ++f)
            af[f] = *(const bf16x8*)(ap + (size_t)f * 16 * lda + ks * 32);
        #pragma unroll
        for (int f = 0; f < 4; ++f)
            bg[f] = *(const bf16x8*)(bp + (size_t)f * 16 * ldb + ks * 32);
        #pragma unroll
        for (int i = 0; i < 4; ++i)
            #pragma unroll
            for (int j = 0; j < 4; ++j)
                acc[i][j] = __builtin_amdgcn_mfma_f32_16x16x32_bf16(
                    af[i], bg[j], acc[i][j], 0, 0, 0);
    }
}

__device__ __forceinline__ void zero_acc(f32x4 acc[4][4]) {
    #pragma unroll
    for (int i = 0; i < 4; ++i)
        #pragma unroll
        for (int j = 0; j < 4; ++j)
            acc[i][j] = f32x4{0.f, 0.f, 0.f, 0.f};
}

// ---------------------------------------------------------------------------
// Projection: C[M x 1024] bf16 = A[M x 512] @ WT[1024 x 512]^T + bias
// ---------------------------------------------------------------------------
__global__ __launch_bounds__(256) void proj_mfma(
    const unsigned short* __restrict__ A, const unsigned short* __restrict__ WT,
    const float* __restrict__ bias_m, const float* __restrict__ bias_c,
    unsigned short* __restrict__ C)
{
    const int wave = threadIdx.x >> 6, lane = threadIdx.x & 63;
    const int m0 = blockIdx.y * 128 + (wave >> 1) * 64;
    const int n0 = blockIdx.x * 128 + (wave & 1) * 64;
    f32x4 acc[4][4]; zero_acc(acc);
    mfma_nt_core<16>(A, WT, KDIM, KDIM, m0, n0, lane, acc);
    const int r = lane & 15, quad = lane >> 4;
    #pragma unroll
    for (int j = 0; j < 4; ++j) {
        const int n = n0 + j * 16 + r;
        const float bv = (n < 512) ? bias_m[n] : bias_c[n - 512];
        #pragma unroll
        for (int i = 0; i < 4; ++i) {
            #pragma unroll
            for (int reg = 0; reg < 4; ++reg) {
                const int m = m0 + i * 16 + quad * 4 + reg;
                C[(size_t)m * 1024 + n] = f2bf(acc[i][j][reg] + bv);
            }
        }
    }
}

// ---------------------------------------------------------------------------
// p_choose: per batch b, p = sigmoid(qm[b] @ km[b]^T / sqrt(512) + r + noise)
// ---------------------------------------------------------------------------
__global__ __launch_bounds__(256) void pchoose_mfma(
    const unsigned short* __restrict__ qp, const unsigned short* __restrict__ kp,
    const float* __restrict__ noise, const float* __restrict__ rp,
    float* __restrict__ p)
{
    const int b = blockIdx.z;
    const unsigned short* A = qp + (size_t)b * QLEN * 1024;
    const unsigned short* B = kp + (size_t)b * KLEN * 1024;
    const int wave = threadIdx.x >> 6, lane = threadIdx.x & 63;
    const int m0 = blockIdx.y * 128 + (wave >> 1) * 64;
    const int n0 = blockIdx.x * 128 + (wave & 1) * 64;
    f32x4 acc[4][4]; zero_acc(acc);
    mfma_nt_core<16>(A, B, 1024, 1024, m0, n0, lane, acc);
    const int r = lane & 15, quad = lane >> 4;
    const float rv = rp[0];
    #pragma unroll
    for (int i = 0; i < 4; ++i) {
        #pragma unroll
        for (int reg = 0; reg < 4; ++reg) {
            const int q = m0 + i * 16 + quad * 4 + reg;
            const size_t rowoff = ((size_t)b * QLEN + q) * KLEN;
            #pragma unroll
            for (int j = 0; j < 4; ++j) {
                const int k = n0 + j * 16 + r;
                const float e = acc[i][j][reg] * INV_SCALE + rv + noise[rowoff + k];
                p[rowoff + k] = 1.0f / (1.0f + expf(-e));
            }
        }
    }
}

// ---------------------------------------------------------------------------
// e_chunk: per (b,h), out[b,h,q,k] = qc_h[b] @ kc_h[b]^T / sqrt(512)
// ---------------------------------------------------------------------------
__global__ __launch_bounds__(256) void echunk_mfma(
    const unsigned short* __restrict__ qp, const unsigned short* __restrict__ kp,
    float* __restrict__ out)
{
    const int z = blockIdx.z, b = z >> 2, h = z & 3;
    const unsigned short* A = qp + (size_t)b * QLEN * 1024 + 512 + h * DKH;
    const unsigned short* B = kp + (size_t)b * KLEN * 1024 + 512 + h * DKH;
    const int wave = threadIdx.x >> 6, lane = threadIdx.x & 63;
    const int m0 = blockIdx.y * 128 + (wave >> 1) * 64;
    const int n0 = blockIdx.x * 128 + (wave & 1) * 64;
    f32x4 acc[4][4]; zero_acc(acc);
    mfma_nt_core<4>(A, B, 1024, 1024, m0, n0, lane, acc);
    const int r = lane & 15, quad = lane >> 4;
    #pragma unroll
    for (int i = 0; i < 4; ++i) {
        #pragma unroll
        for (int reg = 0; reg < 4; ++reg) {
            const int q = m0 + i * 16 + quad * 4 + reg;
            const size_t rowoff = ((size_t)z * QLEN + q) * KLEN;
            #pragma unroll
            for (int j = 0; j < 4; ++j) {
                const int k = n0 + j * 16 + r;
                out[rowoff + k] = acc[i][j][reg] * INV_SCALE;
            }
        }
    }
}

// ---------------------------------------------------------------------------
// 64-lane inclusive prefix sum via DPP (≈6 VALU ops, no LDS round-trips)
// ---------------------------------------------------------------------------
__device__ __forceinline__ float wave_incl_scan(float x)
{
#define DPP_ADD(ctrl, rmask, bctrl)                                            \
    { int _t = __builtin_amdgcn_update_dpp(0, __builtin_bit_cast(int, x),      \
                                           ctrl, rmask, 0xf, bctrl);           \
      x += __builtin_bit_cast(float, _t); }
    DPP_ADD(0x111, 0xf, true)   // row_shr:1
    DPP_ADD(0x112, 0xf, true)   // row_shr:2
    DPP_ADD(0x114, 0xf, true)   // row_shr:4
    DPP_ADD(0x118, 0xf, true)   // row_shr:8
    DPP_ADD(0x142, 0xa, false)  // row_bcast:15 -> rows 1,3
    DPP_ADD(0x143, 0xc, false)  // row_bcast:31 -> rows 2,3
#undef DPP_ADD
    return x;
}

// ---------------------------------------------------------------------------
// alpha_fused: cumprod + alpha recurrence in one kernel, in place over p.
// 1 block/batch, 512 threads (8 waves), 4 contiguous k per lane.
// Per step i (one barrier):
//   stage B: aw-prefix scan for row i (serial path)
//   stage A: log-cumsum scan for row i+1 (independent, pipelined)
// Depth-8 register ring prefetch of p rows (1 float4/lane/row).
// Ring invariant at top of step i: slots hold rows i+1 .. i+ADEPTH.
// (R4 bug: prologue consumed slot 0 / row 0 without refilling it with row
//  ADEPTH, so step 7 read stale row 0 as "row 8" — fixed below.)
// ---------------------------------------------------------------------------
__global__ __launch_bounds__(512, 1) void alpha_fused(float* __restrict__ pa)
{
    const int b = blockIdx.x;
    const int tid = threadIdx.x;               // 0..511
    const int lane = tid & 63, wid = tid >> 6; // 8 waves
    __shared__ __align__(16) float wtA[2][8];
    __shared__ __align__(16) float wtB[2][8];

    float* prow = pa + (size_t)b * QLEN * KLEN + tid * 4;

    // prime prefetch ring with rows 0..7
    float4 pref[ADEPTH];
    #pragma unroll
    for (int d = 0; d < ADEPTH; ++d)
        pref[d] = *(const float4*)(prow + (size_t)d * KLEN);

    float aw[4] = {0.f, 0.f, 0.f, 0.f};
    if (tid == 0) aw[0] = 1.0f;

    float rm[4], rr[4];   // m = p*cp and r = 1/clip(cp) for current row

    // ---- prologue: stage A for row 0 (parity slot 1) ----
    {
        float4 p4 = pref[0];
        pref[0] = *(const float4*)(prow + (size_t)ADEPTH * KLEN);  // refill: row 8
        float pv[4] = {p4.x, p4.y, p4.z, p4.w};
        float exclA[4]; float runA = 0.0f;
        #pragma unroll
        for (int j = 0; j < 4; ++j) {
            float l = logf(fminf(fmaxf(1.0f - pv[j], EPSV), 1.0f));
            exclA[j] = runA; runA += l;
        }
        float totA = wave_incl_scan(runA);
        if (lane == 63) wtA[1][wid] = totA;
        __syncthreads();
        float baseA = totA - runA;
        float4 w0 = *(const float4*)&wtA[1][0];
        float4 w1 = *(const float4*)&wtA[1][4];
        if (wid > 0) baseA += w0.x;
        if (wid > 1) baseA += w0.y;
        if (wid > 2) baseA += w0.z;
        if (wid > 3) baseA += w0.w;
        if (wid > 4) baseA += w1.x;
        if (wid > 5) baseA += w1.y;
        if (wid > 6) baseA += w1.z;
        #pragma unroll
        for (int j = 0; j < 4; ++j) {
            const float cpv = expf(baseA + exclA[j]);
            rm[j] = pv[j] * cpv;
            rr[j] = __builtin_amdgcn_rcpf(fminf(fmaxf(cpv, EPSV), 1.0f));
        }
    }

#define FUSED_STEP(I, DA, PAR)                                                 \
    {                                                                          \
        const int i_ = (I);                                                    \
        /* stage B partials: inclusive prefix of aw*rr for row i */            \
        float inclB[4]; float runB = 0.0f;                                     \
        _Pragma("unroll")                                                      \
        for (int j = 0; j < 4; ++j) { runB = fmaf(aw[j], rr[j], runB); inclB[j] = runB; } \
        float totB = wave_incl_scan(runB);                                     \
        if (lane == 63) wtB[PAR][wid] = totB;                                  \
        /* stage A partials for row i+1 */                                     \
        float4 p4 = {0.f, 0.f, 0.f, 0.f};                                      \
        float exclA[4] = {}; float runA = 0.0f; float totA = 0.0f;             \
        const bool doA = (i_ + 1 < QLEN);                                      \
        if (doA) {                                                             \
            p4 = pref[DA];                                                     \
            if (i_ + 1 + ADEPTH < QLEN)  /* refill freed slot */               \
                pref[DA] = *(const float4*)(prow + (size_t)(i_ + 1 + ADEPTH) * KLEN); \
            float pv0 = p4.x, pv1 = p4.y, pv2 = p4.z, pv3 = p4.w;              \
            float l;                                                           \
            l = logf(fminf(fmaxf(1.0f - pv0, EPSV), 1.0f)); exclA[0] = runA; runA += l; \
            l = logf(fminf(fmaxf(1.0f - pv1, EPSV), 1.0f)); exclA[1] = runA; runA += l; \
            l = logf(fminf(fmaxf(1.0f - pv2, EPSV), 1.0f)); exclA[2] = runA; runA += l; \
            l = logf(fminf(fmaxf(1.0f - pv3, EPSV), 1.0f)); exclA[3] = runA; runA += l; \
            totA = wave_incl_scan(runA);                                       \
            if (lane == 63) wtA[PAR][wid] = totA;                              \
        }                                                                      \
        __syncthreads();                                                       \
        /* finish stage B: alpha row i */                                      \
        {                                                                      \
            float baseB = totB - runB;                                         \
            float4 w0 = *(const float4*)&wtB[PAR][0];                          \
            float4 w1 = *(const float4*)&wtB[PAR][4];                          \
            if (wid > 0) baseB += w0.x;                                        \
            if (wid > 1) baseB += w0.y;                                        \
            if (wid > 2) baseB += w0.z;                                        \
            if (wid > 3) baseB += w0.w;                                        \
            if (wid > 4) baseB += w1.x;                                        \
            if (wid > 5) baseB += w1.y;                                        \
            if (wid > 6) baseB += w1.z;                                        \
            _Pragma("unroll")                                                  \
            for (int j = 0; j < 4; ++j) aw[j] = rm[j] * (baseB + inclB[j]);    \
            float4 ov; ov.x = aw[0]; ov.y = aw[1]; ov.z = aw[2]; ov.w = aw[3]; \
            *(float4*)(prow + (size_t)i_ * KLEN) = ov;                         \
        }                                                                      \
        /* finish stage A: (m, r) for row i+1 */                               \
        if (doA) {                                                             \
            float baseA = totA - runA;                                         \
            float4 w0 = *(const float4*)&wtA[PAR][0];                          \
            float4 w1 = *(const float4*)&wtA[PAR][4];                          \
            if (wid > 0) baseA += w0.x;                                        \
            if (wid > 1) baseA += w0.y;                                        \
            if (wid > 2) baseA += w0.z;                                        \
            if (wid > 3) baseA += w0.w;                                        \
            if (wid > 4) baseA += w1.x;                                        \
            if (wid > 5) baseA += w1.y;                                        \
            if (wid > 6) baseA += w1.z;                                        \
            float pv[4] = {p4.x, p4.y, p4.z, p4.w};                            \
            _Pragma("unroll")                                                  \
            for (int j = 0; j < 4; ++j) {                                      \
                const float cpv = expf(baseA + exclA[j]);                      \
                rm[j] = pv[j] * cpv;                                           \
                rr[j] = __builtin_amdgcn_rcpf(fminf(fmaxf(cpv, EPSV), 1.0f));  \
            }                                                                  \
        }                                                                      \
    }

    for (int io = 0; io < QLEN; io += 8) {
        FUSED_STEP(io + 0, 1, 0)
        FUSED_STEP(io + 1, 2, 1)
        FUSED_STEP(io + 2, 3, 0)
        FUSED_STEP(io + 3, 4, 1)
        FUSED_STEP(io + 4, 5, 0)
        FUSED_STEP(io + 5, 6, 1)
        FUSED_STEP(io + 6, 7, 0)
        FUSED_STEP(io + 7, 0, 1)
    }
#undef FUSED_STEP
}

// ---------------------------------------------------------------------------
// beta: per (b,h,q) row of 2048 (e_chunk in d_out, overwritten)
// ---------------------------------------------------------------------------
__global__ __launch_bounds__(256) void beta_kernel(
    float* __restrict__ eo, const float* __restrict__ alpha)
{
    __shared__ float sse[KLEN + 3];
    __shared__ float su[KLEN + 3];
    __shared__ float wmax[4];

    const int tid = threadIdx.x;
    const int lane = tid & 63, wid = tid >> 6;
    const int row = blockIdx.x;                 // [B*H*Q]
    const int q = row & (QLEN - 1);
    const int b = row >> 10;
    float* erow = eo + (size_t)row * KLEN;
    const float* arow = alpha + ((size_t)b * QLEN + q) * KLEN;

    if (tid < 3) { sse[tid] = 0.0f; su[KLEN + tid] = 0.0f; }

    float ev[8];
    float lm = -INFINITY;
    #pragma unroll
    for (int j = 0; j < 8; ++j) {
        const int k = tid + 256 * j;
        ev[j] = erow[k];
        lm = fmaxf(lm, ev[j]);
    }
    #pragma unroll
    for (int off = 32; off > 0; off >>= 1) lm = fmaxf(lm, __shfl_xor(lm, off));
    if (lane == 0) wmax[wid] = lm;
    __syncthreads();
    const float mx = fmaxf(fmaxf(wmax[0], wmax[1]), fmaxf(wmax[2], wmax[3]));

    #pragma unroll
    for (int j = 0; j < 8; ++j) {
        const int k = tid + 256 * j;
        sse[k + 3] = fmaxf(expf(ev[j] - mx), 1e-5f);
    }
    __syncthreads();

    #pragma unroll
    for (int j = 0; j < 8; ++j) {
        const int k = tid + 256 * j;
        const float denom = sse[k + 3] + sse[k + 2] + sse[k + 1] + sse[k];
        su[k] = arow[k] / denom;
    }
    __syncthreads();

    #pragma unroll
    for (int j = 0; j < 8; ++j) {
        const int k = tid + 256 * j;
        erow[k] = sse[k + 3] * (su[k] + su[k + 1] + su[k + 2] + su[k + 3]);
    }
}

// ---------------------------------------------------------------------------
extern "C" void kernel_launch(void* const* d_in, const int* in_sizes, int n_in,
                              void* d_out, int out_size, void* d_ws, size_t ws_size,
                              hipStream_t stream)
{
    (void)in_sizes; (void)n_in; (void)out_size; (void)ws_size;
    const float* key_enc = (const float*)d_in[0];   // [8,2048,512]
    const float* query   = (const float*)d_in[1];   // [8,256,512]
    const float* noise   = (const float*)d_in[2];   // [8,256,2048]
    const float* Wk_m    = (const float*)d_in[3];
    const float* bk_m    = (const float*)d_in[4];
    const float* Wq_m    = (const float*)d_in[5];
    const float* bq_m    = (const float*)d_in[6];
    const float* rp      = (const float*)d_in[7];
    const float* Wk_c    = (const float*)d_in[8];
    const float* bk_c    = (const float*)d_in[9];
    const float* Wq_c    = (const float*)d_in[10];
    const float* bq_c    = (const float*)d_in[11];
    float* out = (float*)d_out;                     // [8,4,256,2048]

    // workspace layout (bytes)
    char* w = (char*)d_ws;
    unsigned short* kx    = (unsigned short*)w; w += (size_t)BATCH * KLEN * KDIM * 2;   // 16.8 MB
    unsigned short* qx    = (unsigned short*)w; w += (size_t)BATCH * QLEN * KDIM * 2;   //  2.1 MB
    unsigned short* WTk   = (unsigned short*)w; w += (size_t)1024 * KDIM * 2;           //  1.0 MB
    unsigned short* WTq   = (unsigned short*)w; w += (size_t)1024 * KDIM * 2;           //  1.0 MB
    unsigned short* kproj = (unsigned short*)w; w += (size_t)BATCH * KLEN * 1024 * 2;   // 33.6 MB
    unsigned short* qproj = (unsigned short*)w; w += (size_t)BATCH * QLEN * 1024 * 2;   //  4.2 MB
    float* p_alpha = (float*)w;                                                          // 16.8 MB

    // 1) casts
    hipLaunchKernelGGL(cast_bf16, dim3(BATCH * KLEN * KDIM / 4 / 256), dim3(256), 0, stream,
                       key_enc, kx, BATCH * KLEN * KDIM / 4);
    hipLaunchKernelGGL(cast_bf16, dim3(BATCH * QLEN * KDIM / 4 / 256), dim3(256), 0, stream,
                       query, qx, BATCH * QLEN * KDIM / 4);
    hipLaunchKernelGGL(transpose_cast, dim3(16, 16), dim3(32, 8), 0, stream, Wk_m, WTk);
    hipLaunchKernelGGL(transpose_cast, dim3(16, 16), dim3(32, 8), 0, stream, Wk_c, WTk + (size_t)512 * KDIM);
    hipLaunchKernelGGL(transpose_cast, dim3(16, 16), dim3(32, 8), 0, stream, Wq_m, WTq);
    hipLaunchKernelGGL(transpose_cast, dim3(16, 16), dim3(32, 8), 0, stream, Wq_c, WTq + (size_t)512 * KDIM);

    // 2) projections (bf16 MFMA, fused bias, bf16 out)
    hipLaunchKernelGGL(proj_mfma, dim3(8, BATCH * KLEN / 128), dim3(256), 0, stream,
                       kx, WTk, bk_m, bk_c, kproj);
    hipLaunchKernelGGL(proj_mfma, dim3(8, BATCH * QLEN / 128), dim3(256), 0, stream,
                       qx, WTq, bq_m, bq_c, qproj);

    // 3) p_choose (bf16 MFMA + sigmoid epilogue)
    hipLaunchKernelGGL(pchoose_mfma, dim3(KLEN / 128, QLEN / 128, BATCH), dim3(256), 0, stream,
                       qproj, kproj, noise, rp, p_alpha);

    // 4) fused cumprod + alpha recurrence (in place over p)
    hipLaunchKernelGGL(alpha_fused, dim3(BATCH), dim3(512), 0, stream, p_alpha);

    // 5) e_chunk (bf16 MFMA) into d_out
    hipLaunchKernelGGL(echunk_mfma, dim3(KLEN / 128, QLEN / 128, BATCH * NHEADS), dim3(256), 0, stream,
                       qproj, kproj, out);

    // 6) beta (overwrites e_chunk rows in d_out)
    hipLaunchKernelGGL(beta_kernel, dim3(BATCH * NHEADS * QLEN), dim3(256), 0, stream,
                       out, p_alpha);
}

// Round 6
// 495.945 us; speedup vs baseline: 2.1586x; 1.0017x over previous
//
#include <hip/hip_runtime.h>
#include <math.h>

// Problem constants
#define BATCH   8
#define QLEN    256
#define KLEN    2048
#define KDIM    512
#define ADIMC   512
#define NHEADS  4
#define DKH     128
#define CHUNKW  4
#define ADEPTH  8       // alpha prefetch ring depth (rows)

static constexpr float INV_SCALE = 0.04419417382415922f; // 1/sqrt(512)
static constexpr float EPSV = 1e-6f;

typedef __attribute__((ext_vector_type(8))) short bf16x8;
typedef __attribute__((ext_vector_type(4))) float f32x4;

__device__ __forceinline__ unsigned short f2bf(float f) {
    unsigned u = __builtin_bit_cast(unsigned, f);
    u += 0x7fffu + ((u >> 16) & 1u);   // round-to-nearest-even
    return (unsigned short)(u >> 16);
}

// Barrier that waits ONLY on LDS ops (lgkmcnt), leaving global loads/stores
// (vmcnt) in flight across it. __syncthreads() would emit s_waitcnt vmcnt(0)
// and drain the prefetch ring + alpha stores every step (the R5 1940cyc/step
// pathology). Cross-wave data here flows only through LDS, so lgkmcnt(0) is
// sufficient ordering; "memory" clobber stops compiler reordering.
__device__ __forceinline__ void lds_barrier() {
    __asm__ volatile("s_waitcnt lgkmcnt(0)\n\ts_barrier" ::: "memory");
}

// ---------------------------------------------------------------------------
// Elementwise f32 -> bf16 cast (4 elems/thread)
// ---------------------------------------------------------------------------
__global__ __launch_bounds__(256) void cast_bf16(
    const float* __restrict__ x, unsigned short* __restrict__ y, int n4)
{
    int i = blockIdx.x * 256 + threadIdx.x;
    if (i < n4) {
        float4 v = ((const float4*)x)[i];
        ushort4 o;
        o.x = f2bf(v.x); o.y = f2bf(v.y); o.z = f2bf(v.z); o.w = f2bf(v.w);
        ((ushort4*)y)[i] = o;
    }
}

// ---------------------------------------------------------------------------
// Transpose-cast: W [512 x 512] (k-major rows) -> WT [512 x 512] bf16, WT[n][k]
// ---------------------------------------------------------------------------
__global__ __launch_bounds__(256) void transpose_cast(
    const float* __restrict__ W, unsigned short* __restrict__ WT)
{
    __shared__ float tile[32][33];
    const int tx = threadIdx.x;          // 0..31
    const int ty = threadIdx.y;          // 0..7
    const int k0 = blockIdx.y * 32, n0 = blockIdx.x * 32;
    #pragma unroll
    for (int i = 0; i < 32; i += 8)
        tile[ty + i][tx] = W[(size_t)(k0 + ty + i) * KDIM + n0 + tx];
    __syncthreads();
    #pragma unroll
    for (int i = 0; i < 32; i += 8)
        WT[(size_t)(n0 + ty + i) * KDIM + k0 + tx] = f2bf(tile[tx][ty + i]);
}

// ---------------------------------------------------------------------------
// Generic NT MFMA core: wave computes 64x64 f32 tile of A[M,K] @ B[N,K]^T.
// ---------------------------------------------------------------------------
template<int KSTEPS>
__device__ __forceinline__ void mfma_nt_core(
    const unsigned short* __restrict__ A, const unsigned short* __restrict__ B,
    int lda, int ldb, int m0, int n0, int lane, f32x4 acc[4][4])
{
    const int r = lane & 15, quad = lane >> 4;
    const unsigned short* ap = A + (size_t)(m0 + r) * lda + quad * 8;
    const unsigned short* bp = B + (size_t)(n0 + r) * ldb + quad * 8;
    #pragma unroll 4
    for (int ks = 0; ks < KSTEPS; ++ks) {
        bf16x8 af[4], bg[4];
        #pragma unroll
        for (int f = 0; f < 4; ++f)
            af[f] = *(const bf16x8*)(ap + (size_t)f * 16 * lda + ks * 32);
        #pragma unroll
        for (int f = 0; f < 4; ++f)
            bg[f] = *(const bf16x8*)(bp + (size_t)f * 16 * ldb + ks * 32);
        #pragma unroll
        for (int i = 0; i < 4; ++i)
            #pragma unroll
            for (int j = 0; j < 4; ++j)
                acc[i][j] = __builtin_amdgcn_mfma_f32_16x16x32_bf16(
                    af[i], bg[j], acc[i][j], 0, 0, 0);
    }
}

__device__ __forceinline__ void zero_acc(f32x4 acc[4][4]) {
    #pragma unroll
    for (int i = 0; i < 4; ++i)
        #pragma unroll
        for (int j = 0; j < 4; ++j)
            acc[i][j] = f32x4{0.f, 0.f, 0.f, 0.f};
}

// ---------------------------------------------------------------------------
// Projection: C[M x 1024] bf16 = A[M x 512] @ WT[1024 x 512]^T + bias
// ---------------------------------------------------------------------------
__global__ __launch_bounds__(256) void proj_mfma(
    const unsigned short* __restrict__ A, const unsigned short* __restrict__ WT,
    const float* __restrict__ bias_m, const float* __restrict__ bias_c,
    unsigned short* __restrict__ C)
{
    const int wave = threadIdx.x >> 6, lane = threadIdx.x & 63;
    const int m0 = blockIdx.y * 128 + (wave >> 1) * 64;
    const int n0 = blockIdx.x * 128 + (wave & 1) * 64;
    f32x4 acc[4][4]; zero_acc(acc);
    mfma_nt_core<16>(A, WT, KDIM, KDIM, m0, n0, lane, acc);
    const int r = lane & 15, quad = lane >> 4;
    #pragma unroll
    for (int j = 0; j < 4; ++j) {
        const int n = n0 + j * 16 + r;
        const float bv = (n < 512) ? bias_m[n] : bias_c[n - 512];
        #pragma unroll
        for (int i = 0; i < 4; ++i) {
            #pragma unroll
            for (int reg = 0; reg < 4; ++reg) {
                const int m = m0 + i * 16 + quad * 4 + reg;
                C[(size_t)m * 1024 + n] = f2bf(acc[i][j][reg] + bv);
            }
        }
    }
}

// ---------------------------------------------------------------------------
// p_choose: per batch b, p = sigmoid(qm[b] @ km[b]^T / sqrt(512) + r + noise)
// ---------------------------------------------------------------------------
__global__ __launch_bounds__(256) void pchoose_mfma(
    const unsigned short* __restrict__ qp, const unsigned short* __restrict__ kp,
    const float* __restrict__ noise, const float* __restrict__ rp,
    float* __restrict__ p)
{
    const int b = blockIdx.z;
    const unsigned short* A = qp + (size_t)b * QLEN * 1024;
    const unsigned short* B = kp + (size_t)b * KLEN * 1024;
    const int wave = threadIdx.x >> 6, lane = threadIdx.x & 63;
    const int m0 = blockIdx.y * 128 + (wave >> 1) * 64;
    const int n0 = blockIdx.x * 128 + (wave & 1) * 64;
    f32x4 acc[4][4]; zero_acc(acc);
    mfma_nt_core<16>(A, B, 1024, 1024, m0, n0, lane, acc);
    const int r = lane & 15, quad = lane >> 4;
    const float rv = rp[0];
    #pragma unroll
    for (int i = 0; i < 4; ++i) {
        #pragma unroll
        for (int reg = 0; reg < 4; ++reg) {
            const int q = m0 + i * 16 + quad * 4 + reg;
            const size_t rowoff = ((size_t)b * QLEN + q) * KLEN;
            #pragma unroll
            for (int j = 0; j < 4; ++j) {
                const int k = n0 + j * 16 + r;
                const float e = acc[i][j][reg] * INV_SCALE + rv + noise[rowoff + k];
                p[rowoff + k] = 1.0f / (1.0f + expf(-e));
            }
        }
    }
}

// ---------------------------------------------------------------------------
// e_chunk: per (b,h), out[b,h,q,k] = qc_h[b] @ kc_h[b]^T / sqrt(512)
// ---------------------------------------------------------------------------
__global__ __launch_bounds__(256) void echunk_mfma(
    const unsigned short* __restrict__ qp, const unsigned short* __restrict__ kp,
    float* __restrict__ out)
{
    const int z = blockIdx.z, b = z >> 2, h = z & 3;
    const unsigned short* A = qp + (size_t)b * QLEN * 1024 + 512 + h * DKH;
    const unsigned short* B = kp + (size_t)b * KLEN * 1024 + 512 + h * DKH;
    const int wave = threadIdx.x >> 6, lane = threadIdx.x & 63;
    const int m0 = blockIdx.y * 128 + (wave >> 1) * 64;
    const int n0 = blockIdx.x * 128 + (wave & 1) * 64;
    f32x4 acc[4][4]; zero_acc(acc);
    mfma_nt_core<4>(A, B, 1024, 1024, m0, n0, lane, acc);
    const int r = lane & 15, quad = lane >> 4;
    #pragma unroll
    for (int i = 0; i < 4; ++i) {
        #pragma unroll
        for (int reg = 0; reg < 4; ++reg) {
            const int q = m0 + i * 16 + quad * 4 + reg;
            const size_t rowoff = ((size_t)z * QLEN + q) * KLEN;
            #pragma unroll
            for (int j = 0; j < 4; ++j) {
                const int k = n0 + j * 16 + r;
                out[rowoff + k] = acc[i][j][reg] * INV_SCALE;
            }
        }
    }
}

// ---------------------------------------------------------------------------
// 64-lane inclusive prefix sum via DPP (≈6 VALU ops, no LDS round-trips)
// ---------------------------------------------------------------------------
__device__ __forceinline__ float wave_incl_scan(float x)
{
#define DPP_ADD(ctrl, rmask, bctrl)                                            \
    { int _t = __builtin_amdgcn_update_dpp(0, __builtin_bit_cast(int, x),      \
                                           ctrl, rmask, 0xf, bctrl);           \
      x += __builtin_bit_cast(float, _t); }
    DPP_ADD(0x111, 0xf, true)   // row_shr:1
    DPP_ADD(0x112, 0xf, true)   // row_shr:2
    DPP_ADD(0x114, 0xf, true)   // row_shr:4
    DPP_ADD(0x118, 0xf, true)   // row_shr:8
    DPP_ADD(0x142, 0xa, false)  // row_bcast:15 -> rows 1,3
    DPP_ADD(0x143, 0xc, false)  // row_bcast:31 -> rows 2,3
#undef DPP_ADD
    return x;
}

// ---------------------------------------------------------------------------
// alpha_fused: cumprod + alpha recurrence in one kernel, in place over p.
// 1 block/batch, 512 threads (8 waves), 4 contiguous k per lane.
// Per step i (one LDS-only barrier):
//   stage B: aw-prefix scan for row i (serial path)
//   stage A: log-cumsum scan for row i+1 (independent, pipelined)
// Depth-8 register ring prefetch of p rows; ring refill loads and alpha
// stores stay in flight across the barrier (lds_barrier = lgkmcnt only).
// Ring invariant at top of step i: slots hold rows i+1 .. i+ADEPTH.
// ---------------------------------------------------------------------------
__global__ __launch_bounds__(512, 1) void alpha_fused(float* __restrict__ pa)
{
    const int b = blockIdx.x;
    const int tid = threadIdx.x;               // 0..511
    const int lane = tid & 63, wid = tid >> 6; // 8 waves
    __shared__ __align__(16) float wtA[2][8];
    __shared__ __align__(16) float wtB[2][8];

    float* prow = pa + (size_t)b * QLEN * KLEN + tid * 4;

    // prime prefetch ring with rows 0..7
    float4 pref[ADEPTH];
    #pragma unroll
    for (int d = 0; d < ADEPTH; ++d)
        pref[d] = *(const float4*)(prow + (size_t)d * KLEN);

    float aw[4] = {0.f, 0.f, 0.f, 0.f};
    if (tid == 0) aw[0] = 1.0f;

    float rm[4], rr[4];   // m = p*cp and r = 1/clip(cp) for current row

    // ---- prologue: stage A for row 0 (parity slot 1) ----
    {
        float4 p4 = pref[0];
        pref[0] = *(const float4*)(prow + (size_t)ADEPTH * KLEN);  // refill: row 8
        float pv[4] = {p4.x, p4.y, p4.z, p4.w};
        float exclA[4]; float runA = 0.0f;
        #pragma unroll
        for (int j = 0; j < 4; ++j) {
            float l = logf(fminf(fmaxf(1.0f - pv[j], EPSV), 1.0f));
            exclA[j] = runA; runA += l;
        }
        float totA = wave_incl_scan(runA);
        if (lane == 63) wtA[1][wid] = totA;
        lds_barrier();
        float baseA = totA - runA;
        float4 w0 = *(const float4*)&wtA[1][0];
        float4 w1 = *(const float4*)&wtA[1][4];
        if (wid > 0) baseA += w0.x;
        if (wid > 1) baseA += w0.y;
        if (wid > 2) baseA += w0.z;
        if (wid > 3) baseA += w0.w;
        if (wid > 4) baseA += w1.x;
        if (wid > 5) baseA += w1.y;
        if (wid > 6) baseA += w1.z;
        #pragma unroll
        for (int j = 0; j < 4; ++j) {
            const float cpv = expf(baseA + exclA[j]);
            rm[j] = pv[j] * cpv;
            rr[j] = __builtin_amdgcn_rcpf(fminf(fmaxf(cpv, EPSV), 1.0f));
        }
    }

#define FUSED_STEP(I, DA, PAR)                                                 \
    {                                                                          \
        const int i_ = (I);                                                    \
        /* stage B partials: inclusive prefix of aw*rr for row i */            \
        float inclB[4]; float runB = 0.0f;                                     \
        _Pragma("unroll")                                                      \
        for (int j = 0; j < 4; ++j) { runB = fmaf(aw[j], rr[j], runB); inclB[j] = runB; } \
        float totB = wave_incl_scan(runB);                                     \
        if (lane == 63) wtB[PAR][wid] = totB;                                  \
        /* stage A partials for row i+1 */                                     \
        float4 p4 = {0.f, 0.f, 0.f, 0.f};                                      \
        float exclA[4] = {}; float runA = 0.0f; float totA = 0.0f;             \
        const bool doA = (i_ + 1 < QLEN);                                      \
        if (doA) {                                                             \
            p4 = pref[DA];                                                     \
            if (i_ + 1 + ADEPTH < QLEN)  /* refill freed slot */               \
                pref[DA] = *(const float4*)(prow + (size_t)(i_ + 1 + ADEPTH) * KLEN); \
            float pv0 = p4.x, pv1 = p4.y, pv2 = p4.z, pv3 = p4.w;              \
            float l;                                                           \
            l = logf(fminf(fmaxf(1.0f - pv0, EPSV), 1.0f)); exclA[0] = runA; runA += l; \
            l = logf(fminf(fmaxf(1.0f - pv1, EPSV), 1.0f)); exclA[1] = runA; runA += l; \
            l = logf(fminf(fmaxf(1.0f - pv2, EPSV), 1.0f)); exclA[2] = runA; runA += l; \
            l = logf(fminf(fmaxf(1.0f - pv3, EPSV), 1.0f)); exclA[3] = runA; runA += l; \
            totA = wave_incl_scan(runA);                                       \
            if (lane == 63) wtA[PAR][wid] = totA;                              \
        }                                                                      \
        lds_barrier();                                                         \
        /* finish stage B: alpha row i */                                      \
        {                                                                      \
            float baseB = totB - runB;                                         \
            float4 w0 = *(const float4*)&wtB[PAR][0];                          \
            float4 w1 = *(const float4*)&wtB[PAR][4];                          \
            if (wid > 0) baseB += w0.x;                                        \
            if (wid > 1) baseB += w0.y;                                        \
            if (wid > 2) baseB += w0.z;                                        \
            if (wid > 3) baseB += w0.w;                                        \
            if (wid > 4) baseB += w1.x;                                        \
            if (wid > 5) baseB += w1.y;                                        \
            if (wid > 6) baseB += w1.z;                                        \
            _Pragma("unroll")                                                  \
            for (int j = 0; j < 4; ++j) aw[j] = rm[j] * (baseB + inclB[j]);    \
            float4 ov; ov.x = aw[0]; ov.y = aw[1]; ov.z = aw[2]; ov.w = aw[3]; \
            *(float4*)(prow + (size_t)i_ * KLEN) = ov;                         \
        }                                                                      \
        /* finish stage A: (m, r) for row i+1 */                               \
        if (doA) {                                                             \
            float baseA = totA - runA;                                         \
            float4 w0 = *(const float4*)&wtA[PAR][0];                          \
            float4 w1 = *(const float4*)&wtA[PAR][4];                          \
            if (wid > 0) baseA += w0.x;                                        \
            if (wid > 1) baseA += w0.y;                                        \
            if (wid > 2) baseA += w0.z;                                        \
            if (wid > 3) baseA += w0.w;                                        \
            if (wid > 4) baseA += w1.x;                                        \
            if (wid > 5) baseA += w1.y;                                        \
            if (wid > 6) baseA += w1.z;                                        \
            float pv[4] = {p4.x, p4.y, p4.z, p4.w};                            \
            _Pragma("unroll")                                                  \
            for (int j = 0; j < 4; ++j) {                                      \
                const float cpv = expf(baseA + exclA[j]);                      \
                rm[j] = pv[j] * cpv;                                           \
                rr[j] = __builtin_amdgcn_rcpf(fminf(fmaxf(cpv, EPSV), 1.0f));  \
            }                                                                  \
        }                                                                      \
    }

    for (int io = 0; io < QLEN; io += 8) {
        FUSED_STEP(io + 0, 1, 0)
        FUSED_STEP(io + 1, 2, 1)
        FUSED_STEP(io + 2, 3, 0)
        FUSED_STEP(io + 3, 4, 1)
        FUSED_STEP(io + 4, 5, 0)
        FUSED_STEP(io + 5, 6, 1)
        FUSED_STEP(io + 6, 7, 0)
        FUSED_STEP(io + 7, 0, 1)
    }
#undef FUSED_STEP
}

// ---------------------------------------------------------------------------
// beta: per (b,h,q) row of 2048 (e_chunk in d_out, overwritten)
// ---------------------------------------------------------------------------
__global__ __launch_bounds__(256) void beta_kernel(
    float* __restrict__ eo, const float* __restrict__ alpha)
{
    __shared__ float sse[KLEN + 3];
    __shared__ float su[KLEN + 3];
    __shared__ float wmax[4];

    const int tid = threadIdx.x;
    const int lane = tid & 63, wid = tid >> 6;
    const int row = blockIdx.x;                 // [B*H*Q]
    const int q = row & (QLEN - 1);
    const int b = row >> 10;
    float* erow = eo + (size_t)row * KLEN;
    const float* arow = alpha + ((size_t)b * QLEN + q) * KLEN;

    if (tid < 3) { sse[tid] = 0.0f; su[KLEN + tid] = 0.0f; }

    float ev[8];
    float lm = -INFINITY;
    #pragma unroll
    for (int j = 0; j < 8; ++j) {
        const int k = tid + 256 * j;
        ev[j] = erow[k];
        lm = fmaxf(lm, ev[j]);
    }
    #pragma unroll
    for (int off = 32; off > 0; off >>= 1) lm = fmaxf(lm, __shfl_xor(lm, off));
    if (lane == 0) wmax[wid] = lm;
    __syncthreads();
    const float mx = fmaxf(fmaxf(wmax[0], wmax[1]), fmaxf(wmax[2], wmax[3]));

    #pragma unroll
    for (int j = 0; j < 8; ++j) {
        const int k = tid + 256 * j;
        sse[k + 3] = fmaxf(expf(ev[j] - mx), 1e-5f);
    }
    __syncthreads();

    #pragma unroll
    for (int j = 0; j < 8; ++j) {
        const int k = tid + 256 * j;
        const float denom = sse[k + 3] + sse[k + 2] + sse[k + 1] + sse[k];
        su[k] = arow[k] / denom;
    }
    __syncthreads();

    #pragma unroll
    for (int j = 0; j < 8; ++j) {
        const int k = tid + 256 * j;
        erow[k] = sse[k + 3] * (su[k] + su[k + 1] + su[k + 2] + su[k + 3]);
    }
}

// ---------------------------------------------------------------------------
extern "C" void kernel_launch(void* const* d_in, const int* in_sizes, int n_in,
                              void* d_out, int out_size, void* d_ws, size_t ws_size,
                              hipStream_t stream)
{
    (void)in_sizes; (void)n_in; (void)out_size; (void)ws_size;
    const float* key_enc = (const float*)d_in[0];   // [8,2048,512]
    const float* query   = (const float*)d_in[1];   // [8,256,512]
    const float* noise   = (const float*)d_in[2];   // [8,256,2048]
    const float* Wk_m    = (const float*)d_in[3];
    const float* bk_m    = (const float*)d_in[4];
    const float* Wq_m    = (const float*)d_in[5];
    const float* bq_m    = (const float*)d_in[6];
    const float* rp      = (const float*)d_in[7];
    const float* Wk_c    = (const float*)d_in[8];
    const float* bk_c    = (const float*)d_in[9];
    const float* Wq_c    = (const float*)d_in[10];
    const float* bq_c    = (const float*)d_in[11];
    float* out = (float*)d_out;                     // [8,4,256,2048]

    // workspace layout (bytes)
    char* w = (char*)d_ws;
    unsigned short* kx    = (unsigned short*)w; w += (size_t)BATCH * KLEN * KDIM * 2;   // 16.8 MB
    unsigned short* qx    = (unsigned short*)w; w += (size_t)BATCH * QLEN * KDIM * 2;   //  2.1 MB
    unsigned short* WTk   = (unsigned short*)w; w += (size_t)1024 * KDIM * 2;           //  1.0 MB
    unsigned short* WTq   = (unsigned short*)w; w += (size_t)1024 * KDIM * 2;           //  1.0 MB
    unsigned short* kproj = (unsigned short*)w; w += (size_t)BATCH * KLEN * 1024 * 2;   // 33.6 MB
    unsigned short* qproj = (unsigned short*)w; w += (size_t)BATCH * QLEN * 1024 * 2;   //  4.2 MB
    float* p_alpha = (float*)w;                                                          // 16.8 MB

    // 1) casts
    hipLaunchKernelGGL(cast_bf16, dim3(BATCH * KLEN * KDIM / 4 / 256), dim3(256), 0, stream,
                       key_enc, kx, BATCH * KLEN * KDIM / 4);
    hipLaunchKernelGGL(cast_bf16, dim3(BATCH * QLEN * KDIM / 4 / 256), dim3(256), 0, stream,
                       query, qx, BATCH * QLEN * KDIM / 4);
    hipLaunchKernelGGL(transpose_cast, dim3(16, 16), dim3(32, 8), 0, stream, Wk_m, WTk);
    hipLaunchKernelGGL(transpose_cast, dim3(16, 16), dim3(32, 8), 0, stream, Wk_c, WTk + (size_t)512 * KDIM);
    hipLaunchKernelGGL(transpose_cast, dim3(16, 16), dim3(32, 8), 0, stream, Wq_m, WTq);
    hipLaunchKernelGGL(transpose_cast, dim3(16, 16), dim3(32, 8), 0, stream, Wq_c, WTq + (size_t)512 * KDIM);

    // 2) projections (bf16 MFMA, fused bias, bf16 out)
    hipLaunchKernelGGL(proj_mfma, dim3(8, BATCH * KLEN / 128), dim3(256), 0, stream,
                       kx, WTk, bk_m, bk_c, kproj);
    hipLaunchKernelGGL(proj_mfma, dim3(8, BATCH * QLEN / 128), dim3(256), 0, stream,
                       qx, WTq, bq_m, bq_c, qproj);

    // 3) p_choose (bf16 MFMA + sigmoid epilogue)
    hipLaunchKernelGGL(pchoose_mfma, dim3(KLEN / 128, QLEN / 128, BATCH), dim3(256), 0, stream,
                       qproj, kproj, noise, rp, p_alpha);

    // 4) fused cumprod + alpha recurrence (in place over p)
    hipLaunchKernelGGL(alpha_fused, dim3(BATCH), dim3(512), 0, stream, p_alpha);

    // 5) e_chunk (bf16 MFMA) into d_out
    hipLaunchKernelGGL(echunk_mfma, dim3(KLEN / 128, QLEN / 128, BATCH * NHEADS), dim3(256), 0, stream,
                       qproj, kproj, out);

    // 6) beta (overwrites e_chunk rows in d_out)
    hipLaunchKernelGGL(beta_kernel, dim3(BATCH * NHEADS * QLEN), dim3(256), 0, stream,
                       out, p_alpha);
}

// Round 7
// 494.226 us; speedup vs baseline: 2.1661x; 1.0035x over previous
//
#include <hip/hip_runtime.h>
#include <math.h>

// Problem constants
#define BATCH   8
#define QLEN    256
#define KLEN    2048
#define KDIM    512
#define ADIMC   512
#define NHEADS  4
#define DKH     128
#define CHUNKW  4

static constexpr float INV_SCALE = 0.04419417382415922f; // 1/sqrt(512)
static constexpr float EPSV = 1e-6f;

typedef __attribute__((ext_vector_type(8))) short bf16x8;
typedef __attribute__((ext_vector_type(4))) float f32x4;

__device__ __forceinline__ unsigned short f2bf(float f) {
    unsigned u = __builtin_bit_cast(unsigned, f);
    u += 0x7fffu + ((u >> 16) & 1u);   // round-to-nearest-even
    return (unsigned short)(u >> 16);
}

// Barrier waiting only on LDS ops (lgkmcnt); global loads/stores stay in
// flight. The "memory" clobber also PINS ring-refill loads at their issue
// point (a load cannot be moved across a may-write asm), which is what keeps
// the software prefetch ring honest.
__device__ __forceinline__ void lds_barrier() {
    __asm__ volatile("s_waitcnt lgkmcnt(0)\n\ts_barrier" ::: "memory");
}

// ---------------------------------------------------------------------------
// Elementwise f32 -> bf16 cast (4 elems/thread)
// ---------------------------------------------------------------------------
__global__ __launch_bounds__(256) void cast_bf16(
    const float* __restrict__ x, unsigned short* __restrict__ y, int n4)
{
    int i = blockIdx.x * 256 + threadIdx.x;
    if (i < n4) {
        float4 v = ((const float4*)x)[i];
        ushort4 o;
        o.x = f2bf(v.x); o.y = f2bf(v.y); o.z = f2bf(v.z); o.w = f2bf(v.w);
        ((ushort4*)y)[i] = o;
    }
}

// ---------------------------------------------------------------------------
// Transpose-cast: W [512 x 512] (k-major rows) -> WT [512 x 512] bf16, WT[n][k]
// ---------------------------------------------------------------------------
__global__ __launch_bounds__(256) void transpose_cast(
    const float* __restrict__ W, unsigned short* __restrict__ WT)
{
    __shared__ float tile[32][33];
    const int tx = threadIdx.x;          // 0..31
    const int ty = threadIdx.y;          // 0..7
    const int k0 = blockIdx.y * 32, n0 = blockIdx.x * 32;
    #pragma unroll
    for (int i = 0; i < 32; i += 8)
        tile[ty + i][tx] = W[(size_t)(k0 + ty + i) * KDIM + n0 + tx];
    __syncthreads();
    #pragma unroll
    for (int i = 0; i < 32; i += 8)
        WT[(size_t)(n0 + ty + i) * KDIM + k0 + tx] = f2bf(tile[tx][ty + i]);
}

// ---------------------------------------------------------------------------
// Generic NT MFMA core: wave computes 64x64 f32 tile of A[M,K] @ B[N,K]^T.
// ---------------------------------------------------------------------------
template<int KSTEPS>
__device__ __forceinline__ void mfma_nt_core(
    const unsigned short* __restrict__ A, const unsigned short* __restrict__ B,
    int lda, int ldb, int m0, int n0, int lane, f32x4 acc[4][4])
{
    const int r = lane & 15, quad = lane >> 4;
    const unsigned short* ap = A + (size_t)(m0 + r) * lda + quad * 8;
    const unsigned short* bp = B + (size_t)(n0 + r) * ldb + quad * 8;
    #pragma unroll 4
    for (int ks = 0; ks < KSTEPS; ++ks) {
        bf16x8 af[4], bg[4];
        #pragma unroll
        for (int f = 0; f < 4; ++f)
            af[f] = *(const bf16x8*)(ap + (size_t)f * 16 * lda + ks * 32);
        #pragma unroll
        for (int f = 0; f < 4; ++f)
            bg[f] = *(const bf16x8*)(bp + (size_t)f * 16 * ldb + ks * 32);
        #pragma unroll
        for (int i = 0; i < 4; ++i)
            #pragma unroll
            for (int j = 0; j < 4; ++j)
                acc[i][j] = __builtin_amdgcn_mfma_f32_16x16x32_bf16(
                    af[i], bg[j], acc[i][j], 0, 0, 0);
    }
}

__device__ __forceinline__ void zero_acc(f32x4 acc[4][4]) {
    #pragma unroll
    for (int i = 0; i < 4; ++i)
        #pragma unroll
        for (int j = 0; j < 4; ++j)
            acc[i][j] = f32x4{0.f, 0.f, 0.f, 0.f};
}

// ---------------------------------------------------------------------------
// Projection: C[M x 1024] bf16 = A[M x 512] @ WT[1024 x 512]^T + bias
// ---------------------------------------------------------------------------
__global__ __launch_bounds__(256) void proj_mfma(
    const unsigned short* __restrict__ A, const unsigned short* __restrict__ WT,
    const float* __restrict__ bias_m, const float* __restrict__ bias_c,
    unsigned short* __restrict__ C)
{
    const int wave = threadIdx.x >> 6, lane = threadIdx.x & 63;
    const int m0 = blockIdx.y * 128 + (wave >> 1) * 64;
    const int n0 = blockIdx.x * 128 + (wave & 1) * 64;
    f32x4 acc[4][4]; zero_acc(acc);
    mfma_nt_core<16>(A, WT, KDIM, KDIM, m0, n0, lane, acc);
    const int r = lane & 15, quad = lane >> 4;
    #pragma unroll
    for (int j = 0; j < 4; ++j) {
        const int n = n0 + j * 16 + r;
        const float bv = (n < 512) ? bias_m[n] : bias_c[n - 512];
        #pragma unroll
        for (int i = 0; i < 4; ++i) {
            #pragma unroll
            for (int reg = 0; reg < 4; ++reg) {
                const int m = m0 + i * 16 + quad * 4 + reg;
                C[(size_t)m * 1024 + n] = f2bf(acc[i][j][reg] + bv);
            }
        }
    }
}

// ---------------------------------------------------------------------------
// p_choose: per batch b, p = sigmoid(qm[b] @ km[b]^T / sqrt(512) + r + noise)
// ---------------------------------------------------------------------------
__global__ __launch_bounds__(256) void pchoose_mfma(
    const unsigned short* __restrict__ qp, const unsigned short* __restrict__ kp,
    const float* __restrict__ noise, const float* __restrict__ rp,
    float* __restrict__ p)
{
    const int b = blockIdx.z;
    const unsigned short* A = qp + (size_t)b * QLEN * 1024;
    const unsigned short* B = kp + (size_t)b * KLEN * 1024;
    const int wave = threadIdx.x >> 6, lane = threadIdx.x & 63;
    const int m0 = blockIdx.y * 128 + (wave >> 1) * 64;
    const int n0 = blockIdx.x * 128 + (wave & 1) * 64;
    f32x4 acc[4][4]; zero_acc(acc);
    mfma_nt_core<16>(A, B, 1024, 1024, m0, n0, lane, acc);
    const int r = lane & 15, quad = lane >> 4;
    const float rv = rp[0];
    #pragma unroll
    for (int i = 0; i < 4; ++i) {
        #pragma unroll
        for (int reg = 0; reg < 4; ++reg) {
            const int q = m0 + i * 16 + quad * 4 + reg;
            const size_t rowoff = ((size_t)b * QLEN + q) * KLEN;
            #pragma unroll
            for (int j = 0; j < 4; ++j) {
                const int k = n0 + j * 16 + r;
                const float e = acc[i][j][reg] * INV_SCALE + rv + noise[rowoff + k];
                p[rowoff + k] = 1.0f / (1.0f + expf(-e));
            }
        }
    }
}

// ---------------------------------------------------------------------------
// e_chunk: per (b,h), out[b,h,q,k] = qc_h[b] @ kc_h[b]^T / sqrt(512)
// ---------------------------------------------------------------------------
__global__ __launch_bounds__(256) void echunk_mfma(
    const unsigned short* __restrict__ qp, const unsigned short* __restrict__ kp,
    float* __restrict__ out)
{
    const int z = blockIdx.z, b = z >> 2, h = z & 3;
    const unsigned short* A = qp + (size_t)b * QLEN * 1024 + 512 + h * DKH;
    const unsigned short* B = kp + (size_t)b * KLEN * 1024 + 512 + h * DKH;
    const int wave = threadIdx.x >> 6, lane = threadIdx.x & 63;
    const int m0 = blockIdx.y * 128 + (wave >> 1) * 64;
    const int n0 = blockIdx.x * 128 + (wave & 1) * 64;
    f32x4 acc[4][4]; zero_acc(acc);
    mfma_nt_core<4>(A, B, 1024, 1024, m0, n0, lane, acc);
    const int r = lane & 15, quad = lane >> 4;
    #pragma unroll
    for (int i = 0; i < 4; ++i) {
        #pragma unroll
        for (int reg = 0; reg < 4; ++reg) {
            const int q = m0 + i * 16 + quad * 4 + reg;
            const size_t rowoff = ((size_t)z * QLEN + q) * KLEN;
            #pragma unroll
            for (int j = 0; j < 4; ++j) {
                const int k = n0 + j * 16 + r;
                out[rowoff + k] = acc[i][j][reg] * INV_SCALE;
            }
        }
    }
}

// ---------------------------------------------------------------------------
// 64-lane inclusive prefix sum via DPP (≈6 VALU ops, no LDS round-trips)
// ---------------------------------------------------------------------------
__device__ __forceinline__ float wave_incl_scan(float x)
{
#define DPP_ADD(ctrl, rmask, bctrl)                                            \
    { int _t = __builtin_amdgcn_update_dpp(0, __builtin_bit_cast(int, x),      \
                                           ctrl, rmask, 0xf, bctrl);           \
      x += __builtin_bit_cast(float, _t); }
    DPP_ADD(0x111, 0xf, true)   // row_shr:1
    DPP_ADD(0x112, 0xf, true)   // row_shr:2
    DPP_ADD(0x114, 0xf, true)   // row_shr:4
    DPP_ADD(0x118, 0xf, true)   // row_shr:8
    DPP_ADD(0x142, 0xa, false)  // row_bcast:15 -> rows 1,3
    DPP_ADD(0x143, 0xc, false)  // row_bcast:31 -> rows 2,3
#undef DPP_ADD
    return x;
}

// ---------------------------------------------------------------------------
// alpha_fused: cumprod + alpha recurrence in one kernel, in place over p.
// 1 block/batch, 512 threads (8 waves), 4 contiguous k per lane.
// Depth-8 prefetch ring held in 8 NAMED float4 SSA values g0..g7 (an array
// with a conditional refill failed to promote in R5/R6 — VGPR_Count=40 proved
// the ring was demoted and every step ate a full global-load latency).
// Refills are UNCONDITIONAL with a clamped row index; redundant tail loads
// are never consumed. Ring invariant at top of step i: g[(i+1)%8..] hold rows
// i+1 .. i+8 (row index mod 8 = slot).
// Per step (one LDS-only barrier): stage B aw-scan for row i + stage A
// log-cumsum scan for row i+1, totals exchanged through double-buffered LDS.
// ---------------------------------------------------------------------------
__global__ __launch_bounds__(512, 1) void alpha_fused(float* __restrict__ pa)
{
    const int b = blockIdx.x;
    const int tid = threadIdx.x;               // 0..511
    const int lane = tid & 63, wid = tid >> 6; // 8 waves
    __shared__ __align__(16) float wtA[2][8];
    __shared__ __align__(16) float wtB[2][8];

    float* prow = pa + (size_t)b * QLEN * KLEN + tid * 4;

    // prime prefetch ring with rows 0..7 (named SSA values, not an array)
    float4 g0 = *(const float4*)(prow + (size_t)0 * KLEN);
    float4 g1 = *(const float4*)(prow + (size_t)1 * KLEN);
    float4 g2 = *(const float4*)(prow + (size_t)2 * KLEN);
    float4 g3 = *(const float4*)(prow + (size_t)3 * KLEN);
    float4 g4 = *(const float4*)(prow + (size_t)4 * KLEN);
    float4 g5 = *(const float4*)(prow + (size_t)5 * KLEN);
    float4 g6 = *(const float4*)(prow + (size_t)6 * KLEN);
    float4 g7 = *(const float4*)(prow + (size_t)7 * KLEN);

    float aw[4] = {0.f, 0.f, 0.f, 0.f};
    if (tid == 0) aw[0] = 1.0f;

    float rm[4], rr[4];   // m = p*cp and r = 1/clip(cp) for current row

    // ---- prologue: stage A for row 0 (parity slot 1); consume g0, refill row 8
    {
        float4 p4 = g0;
        g0 = *(const float4*)(prow + (size_t)8 * KLEN);
        float pv[4] = {p4.x, p4.y, p4.z, p4.w};
        float exclA[4]; float runA = 0.0f;
        #pragma unroll
        for (int j = 0; j < 4; ++j) {
            float l = logf(fminf(fmaxf(1.0f - pv[j], EPSV), 1.0f));
            exclA[j] = runA; runA += l;
        }
        float totA = wave_incl_scan(runA);
        if (lane == 63) wtA[1][wid] = totA;
        lds_barrier();
        float baseA = totA - runA;
        float4 w0 = *(const float4*)&wtA[1][0];
        float4 w1 = *(const float4*)&wtA[1][4];
        if (wid > 0) baseA += w0.x;
        if (wid > 1) baseA += w0.y;
        if (wid > 2) baseA += w0.z;
        if (wid > 3) baseA += w0.w;
        if (wid > 4) baseA += w1.x;
        if (wid > 5) baseA += w1.y;
        if (wid > 6) baseA += w1.z;
        #pragma unroll
        for (int j = 0; j < 4; ++j) {
            const float cpv = expf(baseA + exclA[j]);
            rm[j] = pv[j] * cpv;
            rr[j] = __builtin_amdgcn_rcpf(fminf(fmaxf(cpv, EPSV), 1.0f));
        }
    }

#define FUSED_STEP(I, GREG, PAR)                                               \
    {                                                                          \
        const int i_ = (I);                                                    \
        /* stage B partials: inclusive prefix of aw*rr for row i */            \
        float inclB[4]; float runB = 0.0f;                                     \
        _Pragma("unroll")                                                      \
        for (int j = 0; j < 4; ++j) { runB = fmaf(aw[j], rr[j], runB); inclB[j] = runB; } \
        float totB = wave_incl_scan(runB);                                     \
        if (lane == 63) wtB[PAR][wid] = totB;                                  \
        /* consume ring slot (row i+1); refill unconditionally (clamped) */    \
        float4 p4 = GREG;                                                      \
        const int rn_ = (i_ + 9 < QLEN) ? (i_ + 9) : (QLEN - 1);               \
        GREG = *(const float4*)(prow + (size_t)rn_ * KLEN);                    \
        /* stage A partials for row i+1 */                                     \
        float exclA[4] = {}; float runA = 0.0f; float totA = 0.0f;             \
        const bool doA = (i_ + 1 < QLEN);                                      \
        if (doA) {                                                             \
            float l;                                                           \
            l = logf(fminf(fmaxf(1.0f - p4.x, EPSV), 1.0f)); exclA[0] = runA; runA += l; \
            l = logf(fminf(fmaxf(1.0f - p4.y, EPSV), 1.0f)); exclA[1] = runA; runA += l; \
            l = logf(fminf(fmaxf(1.0f - p4.z, EPSV), 1.0f)); exclA[2] = runA; runA += l; \
            l = logf(fminf(fmaxf(1.0f - p4.w, EPSV), 1.0f)); exclA[3] = runA; runA += l; \
            totA = wave_incl_scan(runA);                                       \
            if (lane == 63) wtA[PAR][wid] = totA;                              \
        }                                                                      \
        lds_barrier();                                                         \
        /* finish stage B: alpha row i */                                      \
        {                                                                      \
            float baseB = totB - runB;                                         \
            float4 w0 = *(const float4*)&wtB[PAR][0];                          \
            float4 w1 = *(const float4*)&wtB[PAR][4];                          \
            if (wid > 0) baseB += w0.x;                                        \
            if (wid > 1) baseB += w0.y;                                        \
            if (wid > 2) baseB += w0.z;                                        \
            if (wid > 3) baseB += w0.w;                                        \
            if (wid > 4) baseB += w1.x;                                        \
            if (wid > 5) baseB += w1.y;                                        \
            if (wid > 6) baseB += w1.z;                                        \
            _Pragma("unroll")                                                  \
            for (int j = 0; j < 4; ++j) aw[j] = rm[j] * (baseB + inclB[j]);    \
            float4 ov; ov.x = aw[0]; ov.y = aw[1]; ov.z = aw[2]; ov.w = aw[3]; \
            *(float4*)(prow + (size_t)i_ * KLEN) = ov;                         \
        }                                                                      \
        /* finish stage A: (m, r) for row i+1 */                               \
        if (doA) {                                                             \
            float baseA = totA - runA;                                         \
            float4 w0 = *(const float4*)&wtA[PAR][0];                          \
            float4 w1 = *(const float4*)&wtA[PAR][4];                          \
            if (wid > 0) baseA += w0.x;                                        \
            if (wid > 1) baseA += w0.y;                                        \
            if (wid > 2) baseA += w0.z;                                        \
            if (wid > 3) baseA += w0.w;                                        \
            if (wid > 4) baseA += w1.x;                                        \
            if (wid > 5) baseA += w1.y;                                        \
            if (wid > 6) baseA += w1.z;                                        \
            _Pragma("unroll")                                                  \
            for (int j = 0; j < 4; ++j) {                                      \
                const float pvj = (j == 0) ? p4.x : (j == 1) ? p4.y            \
                                 : (j == 2) ? p4.z : p4.w;                     \
                const float cpv = expf(baseA + exclA[j]);                      \
                rm[j] = pvj * cpv;                                             \
                rr[j] = __builtin_amdgcn_rcpf(fminf(fmaxf(cpv, EPSV), 1.0f));  \
            }                                                                  \
        }                                                                      \
    }

    for (int io = 0; io < QLEN; io += 8) {
        FUSED_STEP(io + 0, g1, 0)
        FUSED_STEP(io + 1, g2, 1)
        FUSED_STEP(io + 2, g3, 0)
        FUSED_STEP(io + 3, g4, 1)
        FUSED_STEP(io + 4, g5, 0)
        FUSED_STEP(io + 5, g6, 1)
        FUSED_STEP(io + 6, g7, 0)
        FUSED_STEP(io + 7, g0, 1)
    }
#undef FUSED_STEP
}

// ---------------------------------------------------------------------------
// beta: per (b,h,q) row of 2048 (e_chunk in d_out, overwritten)
// ---------------------------------------------------------------------------
__global__ __launch_bounds__(256) void beta_kernel(
    float* __restrict__ eo, const float* __restrict__ alpha)
{
    __shared__ float sse[KLEN + 3];
    __shared__ float su[KLEN + 3];
    __shared__ float wmax[4];

    const int tid = threadIdx.x;
    const int lane = tid & 63, wid = tid >> 6;
    const int row = blockIdx.x;                 // [B*H*Q]
    const int q = row & (QLEN - 1);
    const int b = row >> 10;
    float* erow = eo + (size_t)row * KLEN;
    const float* arow = alpha + ((size_t)b * QLEN + q) * KLEN;

    if (tid < 3) { sse[tid] = 0.0f; su[KLEN + tid] = 0.0f; }

    float ev[8];
    float lm = -INFINITY;
    #pragma unroll
    for (int j = 0; j < 8; ++j) {
        const int k = tid + 256 * j;
        ev[j] = erow[k];
        lm = fmaxf(lm, ev[j]);
    }
    #pragma unroll
    for (int off = 32; off > 0; off >>= 1) lm = fmaxf(lm, __shfl_xor(lm, off));
    if (lane == 0) wmax[wid] = lm;
    __syncthreads();
    const float mx = fmaxf(fmaxf(wmax[0], wmax[1]), fmaxf(wmax[2], wmax[3]));

    #pragma unroll
    for (int j = 0; j < 8; ++j) {
        const int k = tid + 256 * j;
        sse[k + 3] = fmaxf(expf(ev[j] - mx), 1e-5f);
    }
    __syncthreads();

    #pragma unroll
    for (int j = 0; j < 8; ++j) {
        const int k = tid + 256 * j;
        const float denom = sse[k + 3] + sse[k + 2] + sse[k + 1] + sse[k];
        su[k] = arow[k] / denom;
    }
    __syncthreads();

    #pragma unroll
    for (int j = 0; j < 8; ++j) {
        const int k = tid + 256 * j;
        erow[k] = sse[k + 3] * (su[k] + su[k + 1] + su[k + 2] + su[k + 3]);
    }
}

// ---------------------------------------------------------------------------
extern "C" void kernel_launch(void* const* d_in, const int* in_sizes, int n_in,
                              void* d_out, int out_size, void* d_ws, size_t ws_size,
                              hipStream_t stream)
{
    (void)in_sizes; (void)n_in; (void)out_size; (void)ws_size;
    const float* key_enc = (const float*)d_in[0];   // [8,2048,512]
    const float* query   = (const float*)d_in[1];   // [8,256,512]
    const float* noise   = (const float*)d_in[2];   // [8,256,2048]
    const float* Wk_m    = (const float*)d_in[3];
    const float* bk_m    = (const float*)d_in[4];
    const float* Wq_m    = (const float*)d_in[5];
    const float* bq_m    = (const float*)d_in[6];
    const float* rp      = (const float*)d_in[7];
    const float* Wk_c    = (const float*)d_in[8];
    const float* bk_c    = (const float*)d_in[9];
    const float* Wq_c    = (const float*)d_in[10];
    const float* bq_c    = (const float*)d_in[11];
    float* out = (float*)d_out;                     // [8,4,256,2048]

    // workspace layout (bytes)
    char* w = (char*)d_ws;
    unsigned short* kx    = (unsigned short*)w; w += (size_t)BATCH * KLEN * KDIM * 2;   // 16.8 MB
    unsigned short* qx    = (unsigned short*)w; w += (size_t)BATCH * QLEN * KDIM * 2;   //  2.1 MB
    unsigned short* WTk   = (unsigned short*)w; w += (size_t)1024 * KDIM * 2;           //  1.0 MB
    unsigned short* WTq   = (unsigned short*)w; w += (size_t)1024 * KDIM * 2;           //  1.0 MB
    unsigned short* kproj = (unsigned short*)w; w += (size_t)BATCH * KLEN * 1024 * 2;   // 33.6 MB
    unsigned short* qproj = (unsigned short*)w; w += (size_t)BATCH * QLEN * 1024 * 2;   //  4.2 MB
    float* p_alpha = (float*)w;                                                          // 16.8 MB

    // 1) casts
    hipLaunchKernelGGL(cast_bf16, dim3(BATCH * KLEN * KDIM / 4 / 256), dim3(256), 0, stream,
                       key_enc, kx, BATCH * KLEN * KDIM / 4);
    hipLaunchKernelGGL(cast_bf16, dim3(BATCH * QLEN * KDIM / 4 / 256), dim3(256), 0, stream,
                       query, qx, BATCH * QLEN * KDIM / 4);
    hipLaunchKernelGGL(transpose_cast, dim3(16, 16), dim3(32, 8), 0, stream, Wk_m, WTk);
    hipLaunchKernelGGL(transpose_cast, dim3(16, 16), dim3(32, 8), 0, stream, Wk_c, WTk + (size_t)512 * KDIM);
    hipLaunchKernelGGL(transpose_cast, dim3(16, 16), dim3(32, 8), 0, stream, Wq_m, WTq);
    hipLaunchKernelGGL(transpose_cast, dim3(16, 16), dim3(32, 8), 0, stream, Wq_c, WTq + (size_t)512 * KDIM);

    // 2) projections (bf16 MFMA, fused bias, bf16 out)
    hipLaunchKernelGGL(proj_mfma, dim3(8, BATCH * KLEN / 128), dim3(256), 0, stream,
                       kx, WTk, bk_m, bk_c, kproj);
    hipLaunchKernelGGL(proj_mfma, dim3(8, BATCH * QLEN / 128), dim3(256), 0, stream,
                       qx, WTq, bq_m, bq_c, qproj);

    // 3) p_choose (bf16 MFMA + sigmoid epilogue)
    hipLaunchKernelGGL(pchoose_mfma, dim3(KLEN / 128, QLEN / 128, BATCH), dim3(256), 0, stream,
                       qproj, kproj, noise, rp, p_alpha);

    // 4) fused cumprod + alpha recurrence (in place over p)
    hipLaunchKernelGGL(alpha_fused, dim3(BATCH), dim3(512), 0, stream, p_alpha);

    // 5) e_chunk (bf16 MFMA) into d_out
    hipLaunchKernelGGL(echunk_mfma, dim3(KLEN / 128, QLEN / 128, BATCH * NHEADS), dim3(256), 0, stream,
                       qproj, kproj, out);

    // 6) beta (overwrites e_chunk rows in d_out)
    hipLaunchKernelGGL(beta_kernel, dim3(BATCH * NHEADS * QLEN), dim3(256), 0, stream,
                       out, p_alpha);
}

// Round 8
// 382.778 us; speedup vs baseline: 2.7968x; 1.2912x over previous
//
#include <hip/hip_runtime.h>
#include <math.h>

// Problem constants
#define BATCH   8
#define QLEN    256
#define KLEN    2048
#define KDIM    512
#define ADIMC   512
#define NHEADS  4
#define DKH     128
#define CHUNKW  4

static constexpr float INV_SCALE = 0.04419417382415922f; // 1/sqrt(512)
static constexpr float EPSV = 1e-6f;

typedef __attribute__((ext_vector_type(8))) short bf16x8;
typedef __attribute__((ext_vector_type(4))) float f32x4;

__device__ __forceinline__ unsigned short f2bf(float f) {
    unsigned u = __builtin_bit_cast(unsigned, f);
    u += 0x7fffu + ((u >> 16) & 1u);   // round-to-nearest-even
    return (unsigned short)(u >> 16);
}

// Barrier waiting only on LDS ops (lgkmcnt); global loads/stores stay in flight.
__device__ __forceinline__ void lds_barrier() {
    __asm__ volatile("s_waitcnt lgkmcnt(0)\n\ts_barrier" ::: "memory");
}

// ---------------------------------------------------------------------------
// Elementwise f32 -> bf16 cast (4 elems/thread)
// ---------------------------------------------------------------------------
__global__ __launch_bounds__(256) void cast_bf16(
    const float* __restrict__ x, unsigned short* __restrict__ y, int n4)
{
    int i = blockIdx.x * 256 + threadIdx.x;
    if (i < n4) {
        float4 v = ((const float4*)x)[i];
        ushort4 o;
        o.x = f2bf(v.x); o.y = f2bf(v.y); o.z = f2bf(v.z); o.w = f2bf(v.w);
        ((ushort4*)y)[i] = o;
    }
}

// ---------------------------------------------------------------------------
// Transpose-cast: W [512 x 512] (k-major rows) -> WT [512 x 512] bf16, WT[n][k]
// ---------------------------------------------------------------------------
__global__ __launch_bounds__(256) void transpose_cast(
    const float* __restrict__ W, unsigned short* __restrict__ WT)
{
    __shared__ float tile[32][33];
    const int tx = threadIdx.x;          // 0..31
    const int ty = threadIdx.y;          // 0..7
    const int k0 = blockIdx.y * 32, n0 = blockIdx.x * 32;
    #pragma unroll
    for (int i = 0; i < 32; i += 8)
        tile[ty + i][tx] = W[(size_t)(k0 + ty + i) * KDIM + n0 + tx];
    __syncthreads();
    #pragma unroll
    for (int i = 0; i < 32; i += 8)
        WT[(size_t)(n0 + ty + i) * KDIM + k0 + tx] = f2bf(tile[tx][ty + i]);
}

// ---------------------------------------------------------------------------
// Generic NT MFMA core: wave computes 64x64 f32 tile of A[M,K] @ B[N,K]^T.
// ---------------------------------------------------------------------------
template<int KSTEPS>
__device__ __forceinline__ void mfma_nt_core(
    const unsigned short* __restrict__ A, const unsigned short* __restrict__ B,
    int lda, int ldb, int m0, int n0, int lane, f32x4 acc[4][4])
{
    const int r = lane & 15, quad = lane >> 4;
    const unsigned short* ap = A + (size_t)(m0 + r) * lda + quad * 8;
    const unsigned short* bp = B + (size_t)(n0 + r) * ldb + quad * 8;
    #pragma unroll 4
    for (int ks = 0; ks < KSTEPS; ++ks) {
        bf16x8 af[4], bg[4];
        #pragma unroll
        for (int f = 0; f < 4; ++f)
            af[f] = *(const bf16x8*)(ap + (size_t)f * 16 * lda + ks * 32);
        #pragma unroll
        for (int f = 0; f < 4; ++f)
            bg[f] = *(const bf16x8*)(bp + (size_t)f * 16 * ldb + ks * 32);
        #pragma unroll
        for (int i = 0; i < 4; ++i)
            #pragma unroll
            for (int j = 0; j < 4; ++j)
                acc[i][j] = __builtin_amdgcn_mfma_f32_16x16x32_bf16(
                    af[i], bg[j], acc[i][j], 0, 0, 0);
    }
}

__device__ __forceinline__ void zero_acc(f32x4 acc[4][4]) {
    #pragma unroll
    for (int i = 0; i < 4; ++i)
        #pragma unroll
        for (int j = 0; j < 4; ++j)
            acc[i][j] = f32x4{0.f, 0.f, 0.f, 0.f};
}

// ---------------------------------------------------------------------------
// Projection: C[M x 1024] bf16 = A[M x 512] @ WT[1024 x 512]^T + bias
// ---------------------------------------------------------------------------
__global__ __launch_bounds__(256) void proj_mfma(
    const unsigned short* __restrict__ A, const unsigned short* __restrict__ WT,
    const float* __restrict__ bias_m, const float* __restrict__ bias_c,
    unsigned short* __restrict__ C)
{
    const int wave = threadIdx.x >> 6, lane = threadIdx.x & 63;
    const int m0 = blockIdx.y * 128 + (wave >> 1) * 64;
    const int n0 = blockIdx.x * 128 + (wave & 1) * 64;
    f32x4 acc[4][4]; zero_acc(acc);
    mfma_nt_core<16>(A, WT, KDIM, KDIM, m0, n0, lane, acc);
    const int r = lane & 15, quad = lane >> 4;
    #pragma unroll
    for (int j = 0; j < 4; ++j) {
        const int n = n0 + j * 16 + r;
        const float bv = (n < 512) ? bias_m[n] : bias_c[n - 512];
        #pragma unroll
        for (int i = 0; i < 4; ++i) {
            #pragma unroll
            for (int reg = 0; reg < 4; ++reg) {
                const int m = m0 + i * 16 + quad * 4 + reg;
                C[(size_t)m * 1024 + n] = f2bf(acc[i][j][reg] + bv);
            }
        }
    }
}

// ---------------------------------------------------------------------------
// p_choose: per batch b, p = sigmoid(qm[b] @ km[b]^T / sqrt(512) + r + noise)
// ---------------------------------------------------------------------------
__global__ __launch_bounds__(256) void pchoose_mfma(
    const unsigned short* __restrict__ qp, const unsigned short* __restrict__ kp,
    const float* __restrict__ noise, const float* __restrict__ rp,
    float* __restrict__ p)
{
    const int b = blockIdx.z;
    const unsigned short* A = qp + (size_t)b * QLEN * 1024;
    const unsigned short* B = kp + (size_t)b * KLEN * 1024;
    const int wave = threadIdx.x >> 6, lane = threadIdx.x & 63;
    const int m0 = blockIdx.y * 128 + (wave >> 1) * 64;
    const int n0 = blockIdx.x * 128 + (wave & 1) * 64;
    f32x4 acc[4][4]; zero_acc(acc);
    mfma_nt_core<16>(A, B, 1024, 1024, m0, n0, lane, acc);
    const int r = lane & 15, quad = lane >> 4;
    const float rv = rp[0];
    #pragma unroll
    for (int i = 0; i < 4; ++i) {
        #pragma unroll
        for (int reg = 0; reg < 4; ++reg) {
            const int q = m0 + i * 16 + quad * 4 + reg;
            const size_t rowoff = ((size_t)b * QLEN + q) * KLEN;
            #pragma unroll
            for (int j = 0; j < 4; ++j) {
                const int k = n0 + j * 16 + r;
                const float e = acc[i][j][reg] * INV_SCALE + rv + noise[rowoff + k];
                p[rowoff + k] = __builtin_amdgcn_rcpf(1.0f + __expf(-e));
            }
        }
    }
}

// ---------------------------------------------------------------------------
// e_chunk: per (b,h), out[b,h,q,k] = qc_h[b] @ kc_h[b]^T / sqrt(512)
// ---------------------------------------------------------------------------
__global__ __launch_bounds__(256) void echunk_mfma(
    const unsigned short* __restrict__ qp, const unsigned short* __restrict__ kp,
    float* __restrict__ out)
{
    const int z = blockIdx.z, b = z >> 2, h = z & 3;
    const unsigned short* A = qp + (size_t)b * QLEN * 1024 + 512 + h * DKH;
    const unsigned short* B = kp + (size_t)b * KLEN * 1024 + 512 + h * DKH;
    const int wave = threadIdx.x >> 6, lane = threadIdx.x & 63;
    const int m0 = blockIdx.y * 128 + (wave >> 1) * 64;
    const int n0 = blockIdx.x * 128 + (wave & 1) * 64;
    f32x4 acc[4][4]; zero_acc(acc);
    mfma_nt_core<4>(A, B, 1024, 1024, m0, n0, lane, acc);
    const int r = lane & 15, quad = lane >> 4;
    #pragma unroll
    for (int i = 0; i < 4; ++i) {
        #pragma unroll
        for (int reg = 0; reg < 4; ++reg) {
            const int q = m0 + i * 16 + quad * 4 + reg;
            const size_t rowoff = ((size_t)z * QLEN + q) * KLEN;
            #pragma unroll
            for (int j = 0; j < 4; ++j) {
                const int k = n0 + j * 16 + r;
                out[rowoff + k] = acc[i][j][reg] * INV_SCALE;
            }
        }
    }
}

// ---------------------------------------------------------------------------
// 64-lane inclusive prefix sum via DPP (≈6 VALU ops, no LDS round-trips)
// ---------------------------------------------------------------------------
__device__ __forceinline__ float wave_incl_scan(float x)
{
#define DPP_ADD(ctrl, rmask, bctrl)                                            \
    { int _t = __builtin_amdgcn_update_dpp(0, __builtin_bit_cast(int, x),      \
                                           ctrl, rmask, 0xf, bctrl);           \
      x += __builtin_bit_cast(float, _t); }
    DPP_ADD(0x111, 0xf, true)   // row_shr:1
    DPP_ADD(0x112, 0xf, true)   // row_shr:2
    DPP_ADD(0x114, 0xf, true)   // row_shr:4
    DPP_ADD(0x118, 0xf, true)   // row_shr:8
    DPP_ADD(0x142, 0xa, false)  // row_bcast:15 -> rows 1,3
    DPP_ADD(0x143, 0xc, false)  // row_bcast:31 -> rows 2,3
#undef DPP_ADD
    return x;
}

// ---------------------------------------------------------------------------
// cumprod_mr: per (b,q) row (2048 independent blocks, fully parallel):
//   cp = exp(exclusive_cumsum(log(clip(1-p,1e-6,1))))
//   m  = p * cp ;  r = 1/clip(cp,1e-6,1)
// Fast intrinsics (__logf/__expf -> v_log_f32/v_exp_f32): this kernel absorbs
// ALL transcendental work so the serial alpha_scan stays lean (R7 post-mortem:
// alpha_fused was VALU-throughput-bound at 82% of its 8-CU ceiling on libm
// log/exp recompute).
// ---------------------------------------------------------------------------
__global__ __launch_bounds__(256) void cumprod_mr(
    const float* __restrict__ p, float* __restrict__ mArr, float* __restrict__ rArr)
{
    const size_t row = blockIdx.x;
    const float* pr = p + row * KLEN;
    float* mr = mArr + row * KLEN;
    float* rr = rArr + row * KLEN;
    const int tid = threadIdx.x;
    const int lane = tid & 63, wid = tid >> 6;
    __shared__ float waveTot[4];

    float4 v0 = *(const float4*)(pr + tid * 8);
    float4 v1 = *(const float4*)(pr + tid * 8 + 4);
    float pv[8] = {v0.x, v0.y, v0.z, v0.w, v1.x, v1.y, v1.z, v1.w};
    float excl[8];
    float run = 0.0f;
    #pragma unroll
    for (int j = 0; j < 8; ++j) {
        float l = __logf(fminf(fmaxf(1.0f - pv[j], EPSV), 1.0f));
        excl[j] = run;
        run += l;
    }
    float s = wave_incl_scan(run);
    if (lane == 63) waveTot[wid] = s;
    __syncthreads();
    float wex = 0.0f;
    for (int w = 0; w < wid; ++w) wex += waveTot[w];
    const float texcl = wex + s - run;

    float mv[8], rv[8];
    #pragma unroll
    for (int j = 0; j < 8; ++j) {
        const float cpv = __expf(texcl + excl[j]);
        mv[j] = pv[j] * cpv;
        rv[j] = __builtin_amdgcn_rcpf(fminf(fmaxf(cpv, EPSV), 1.0f));
    }
    *(float4*)(mr + tid * 8)     = *(float4*)&mv[0];
    *(float4*)(mr + tid * 8 + 4) = *(float4*)&mv[4];
    *(float4*)(rr + tid * 8)     = *(float4*)&rv[0];
    *(float4*)(rr + tid * 8 + 4) = *(float4*)&rv[4];
}

// ---------------------------------------------------------------------------
// alpha_scan: pure recurrence over q, m/r precomputed. 1 block/batch,
// 512 threads (8 waves), 4 contiguous k per lane. Per step: 4 fmaf prefix,
// DPP wave scan, one LDS totals exchange (double-buffered parity), 4 mul,
// store. ~45 VALU instrs/step — exchange latency bound, not VALU bound.
// Depth-2 named ping-pong prefetch of next (m,r) rows.
// ---------------------------------------------------------------------------
__global__ __launch_bounds__(512, 1) void alpha_scan(
    const float* __restrict__ mArr, const float* __restrict__ rArr,
    float* __restrict__ alpha)
{
    const int b = blockIdx.x;
    const int tid = threadIdx.x;               // 0..511
    const int lane = tid & 63, wid = tid >> 6; // 8 waves
    __shared__ __align__(16) float wt[2][8];

    const float* mrow = mArr + (size_t)b * QLEN * KLEN + tid * 4;
    const float* rrow = rArr + (size_t)b * QLEN * KLEN + tid * 4;
    float* arow = alpha + (size_t)b * QLEN * KLEN + tid * 4;

    float aw0 = 0.f, aw1 = 0.f, aw2 = 0.f, aw3 = 0.f;
    if (tid == 0) aw0 = 1.0f;   // aw_prev one-hot at k=0

    // preload rows 0 and 1 (named SSA ping-pong)
    float4 mA = *(const float4*)(mrow);
    float4 rA = *(const float4*)(rrow);
    float4 mB = *(const float4*)(mrow + KLEN);
    float4 rB = *(const float4*)(rrow + KLEN);

#define ASTEP(I, MREG, RREG)                                                   \
    {                                                                          \
        const int i_ = (I);                                                    \
        float4 mc = MREG, rc = RREG;                                           \
        const int rn_ = (i_ + 2 < QLEN) ? (i_ + 2) : (QLEN - 1);               \
        MREG = *(const float4*)(mrow + (size_t)rn_ * KLEN);                    \
        RREG = *(const float4*)(rrow + (size_t)rn_ * KLEN);                    \
        float run = 0.0f, i0, i1, i2, i3;                                      \
        run = fmaf(aw0, rc.x, run); i0 = run;                                  \
        run = fmaf(aw1, rc.y, run); i1 = run;                                  \
        run = fmaf(aw2, rc.z, run); i2 = run;                                  \
        run = fmaf(aw3, rc.w, run); i3 = run;                                  \
        float tot = wave_incl_scan(run);                                       \
        if (lane == 63) wt[i_ & 1][wid] = tot;                                 \
        lds_barrier();                                                         \
        float base = tot - run;                                                \
        float4 w0 = *(const float4*)&wt[i_ & 1][0];                            \
        float4 w1 = *(const float4*)&wt[i_ & 1][4];                            \
        if (wid > 0) base += w0.x;                                             \
        if (wid > 1) base += w0.y;                                             \
        if (wid > 2) base += w0.z;                                             \
        if (wid > 3) base += w0.w;                                             \
        if (wid > 4) base += w1.x;                                             \
        if (wid > 5) base += w1.y;                                             \
        if (wid > 6) base += w1.z;                                             \
        aw0 = mc.x * (base + i0);                                              \
        aw1 = mc.y * (base + i1);                                              \
        aw2 = mc.z * (base + i2);                                              \
        aw3 = mc.w * (base + i3);                                              \
        float4 ov; ov.x = aw0; ov.y = aw1; ov.z = aw2; ov.w = aw3;             \
        *(float4*)(arow + (size_t)i_ * KLEN) = ov;                             \
    }

    for (int io = 0; io < QLEN; io += 2) {
        ASTEP(io + 0, mA, rA)
        ASTEP(io + 1, mB, rB)
    }
#undef ASTEP
}

// ---------------------------------------------------------------------------
// beta: per (b,h,q) row of 2048 (e_chunk in d_out, overwritten)
// ---------------------------------------------------------------------------
__global__ __launch_bounds__(256) void beta_kernel(
    float* __restrict__ eo, const float* __restrict__ alpha)
{
    __shared__ float sse[KLEN + 3];
    __shared__ float su[KLEN + 3];
    __shared__ float wmax[4];

    const int tid = threadIdx.x;
    const int lane = tid & 63, wid = tid >> 6;
    const int row = blockIdx.x;                 // [B*H*Q]
    const int q = row & (QLEN - 1);
    const int b = row >> 10;
    float* erow = eo + (size_t)row * KLEN;
    const float* arow = alpha + ((size_t)b * QLEN + q) * KLEN;

    if (tid < 3) { sse[tid] = 0.0f; su[KLEN + tid] = 0.0f; }

    float ev[8];
    float lm = -INFINITY;
    #pragma unroll
    for (int j = 0; j < 8; ++j) {
        const int k = tid + 256 * j;
        ev[j] = erow[k];
        lm = fmaxf(lm, ev[j]);
    }
    #pragma unroll
    for (int off = 32; off > 0; off >>= 1) lm = fmaxf(lm, __shfl_xor(lm, off));
    if (lane == 0) wmax[wid] = lm;
    __syncthreads();
    const float mx = fmaxf(fmaxf(wmax[0], wmax[1]), fmaxf(wmax[2], wmax[3]));

    #pragma unroll
    for (int j = 0; j < 8; ++j) {
        const int k = tid + 256 * j;
        sse[k + 3] = fmaxf(__expf(ev[j] - mx), 1e-5f);
    }
    __syncthreads();

    #pragma unroll
    for (int j = 0; j < 8; ++j) {
        const int k = tid + 256 * j;
        const float denom = sse[k + 3] + sse[k + 2] + sse[k + 1] + sse[k];
        su[k] = arow[k] * __builtin_amdgcn_rcpf(denom);
    }
    __syncthreads();

    #pragma unroll
    for (int j = 0; j < 8; ++j) {
        const int k = tid + 256 * j;
        erow[k] = sse[k + 3] * (su[k] + su[k + 1] + su[k + 2] + su[k + 3]);
    }
}

// ---------------------------------------------------------------------------
extern "C" void kernel_launch(void* const* d_in, const int* in_sizes, int n_in,
                              void* d_out, int out_size, void* d_ws, size_t ws_size,
                              hipStream_t stream)
{
    (void)in_sizes; (void)n_in; (void)out_size; (void)ws_size;
    const float* key_enc = (const float*)d_in[0];   // [8,2048,512]
    const float* query   = (const float*)d_in[1];   // [8,256,512]
    const float* noise   = (const float*)d_in[2];   // [8,256,2048]
    const float* Wk_m    = (const float*)d_in[3];
    const float* bk_m    = (const float*)d_in[4];
    const float* Wq_m    = (const float*)d_in[5];
    const float* bq_m    = (const float*)d_in[6];
    const float* rp      = (const float*)d_in[7];
    const float* Wk_c    = (const float*)d_in[8];
    const float* bk_c    = (const float*)d_in[9];
    const float* Wq_c    = (const float*)d_in[10];
    const float* bq_c    = (const float*)d_in[11];
    float* out = (float*)d_out;                     // [8,4,256,2048]

    // workspace layout (bytes)
    char* w = (char*)d_ws;
    unsigned short* kx    = (unsigned short*)w; w += (size_t)BATCH * KLEN * KDIM * 2;   // 16.8 MB
    unsigned short* qx    = (unsigned short*)w; w += (size_t)BATCH * QLEN * KDIM * 2;   //  2.1 MB
    unsigned short* WTk   = (unsigned short*)w; w += (size_t)1024 * KDIM * 2;           //  1.0 MB
    unsigned short* WTq   = (unsigned short*)w; w += (size_t)1024 * KDIM * 2;           //  1.0 MB
    unsigned short* kproj = (unsigned short*)w; w += (size_t)BATCH * KLEN * 1024 * 2;   // 33.6 MB
    unsigned short* qproj = (unsigned short*)w; w += (size_t)BATCH * QLEN * 1024 * 2;   //  4.2 MB
    float* p_alpha = (float*)w; w += (size_t)BATCH * QLEN * KLEN * 4;                   // 16.8 MB
    float* mArr    = (float*)w; w += (size_t)BATCH * QLEN * KLEN * 4;                   // 16.8 MB
    float* rArr    = (float*)w;                                                         // 16.8 MB

    // 1) casts
    hipLaunchKernelGGL(cast_bf16, dim3(BATCH * KLEN * KDIM / 4 / 256), dim3(256), 0, stream,
                       key_enc, kx, BATCH * KLEN * KDIM / 4);
    hipLaunchKernelGGL(cast_bf16, dim3(BATCH * QLEN * KDIM / 4 / 256), dim3(256), 0, stream,
                       query, qx, BATCH * QLEN * KDIM / 4);
    hipLaunchKernelGGL(transpose_cast, dim3(16, 16), dim3(32, 8), 0, stream, Wk_m, WTk);
    hipLaunchKernelGGL(transpose_cast, dim3(16, 16), dim3(32, 8), 0, stream, Wk_c, WTk + (size_t)512 * KDIM);
    hipLaunchKernelGGL(transpose_cast, dim3(16, 16), dim3(32, 8), 0, stream, Wq_m, WTq);
    hipLaunchKernelGGL(transpose_cast, dim3(16, 16), dim3(32, 8), 0, stream, Wq_c, WTq + (size_t)512 * KDIM);

    // 2) projections (bf16 MFMA, fused bias, bf16 out)
    hipLaunchKernelGGL(proj_mfma, dim3(8, BATCH * KLEN / 128), dim3(256), 0, stream,
                       kx, WTk, bk_m, bk_c, kproj);
    hipLaunchKernelGGL(proj_mfma, dim3(8, BATCH * QLEN / 128), dim3(256), 0, stream,
                       qx, WTq, bq_m, bq_c, qproj);

    // 3) p_choose (bf16 MFMA + fast sigmoid epilogue)
    hipLaunchKernelGGL(pchoose_mfma, dim3(KLEN / 128, QLEN / 128, BATCH), dim3(256), 0, stream,
                       qproj, kproj, noise, rp, p_alpha);

    // 4) cumprod -> (m, r)  (parallel, absorbs all transcendentals)
    hipLaunchKernelGGL(cumprod_mr, dim3(BATCH * QLEN), dim3(256), 0, stream,
                       p_alpha, mArr, rArr);

    // 5) alpha recurrence (serial, lean) — writes over dead p buffer
    hipLaunchKernelGGL(alpha_scan, dim3(BATCH), dim3(512), 0, stream,
                       mArr, rArr, p_alpha);

    // 6) e_chunk (bf16 MFMA) into d_out
    hipLaunchKernelGGL(echunk_mfma, dim3(KLEN / 128, QLEN / 128, BATCH * NHEADS), dim3(256), 0, stream,
                       qproj, kproj, out);

    // 7) beta (overwrites e_chunk rows in d_out)
    hipLaunchKernelGGL(beta_kernel, dim3(BATCH * NHEADS * QLEN), dim3(256), 0, stream,
                       out, p_alpha);
}

// Round 9
// 323.925 us; speedup vs baseline: 3.3049x; 1.1817x over previous
//
#include <hip/hip_runtime.h>
#include <math.h>

// Problem constants
#define BATCH   8
#define QLEN    256
#define KLEN    2048
#define KDIM    512
#define ADIMC   512
#define NHEADS  4
#define DKH     128
#define CHUNKW  4

static constexpr float INV_SCALE = 0.04419417382415922f; // 1/sqrt(512)
static constexpr float EPSV = 1e-6f;

typedef __attribute__((ext_vector_type(8))) short bf16x8;
typedef __attribute__((ext_vector_type(4))) float f32x4;

__device__ __forceinline__ unsigned short f2bf(float f) {
    unsigned u = __builtin_bit_cast(unsigned, f);
    u += 0x7fffu + ((u >> 16) & 1u);   // round-to-nearest-even
    return (unsigned short)(u >> 16);
}

// Barrier waiting only on LDS ops (lgkmcnt); global loads/stores stay in flight.
__device__ __forceinline__ void lds_barrier() {
    __asm__ volatile("s_waitcnt lgkmcnt(0)\n\ts_barrier" ::: "memory");
}

// Async global->LDS, 16 B per lane. HW rule: data lands at wave-uniform
// lds base + lane*16 (no per-lane scatter) — LDS layout below is built for it.
__device__ __forceinline__ void gload_lds16(const void* g, void* l) {
    __builtin_amdgcn_global_load_lds(
        (const __attribute__((address_space(1))) void*)g,
        (__attribute__((address_space(3))) void*)l, 16, 0, 0);
}

// ---------------------------------------------------------------------------
// Elementwise f32 -> bf16 cast (4 elems/thread)
// ---------------------------------------------------------------------------
__global__ __launch_bounds__(256) void cast_bf16(
    const float* __restrict__ x, unsigned short* __restrict__ y, int n4)
{
    int i = blockIdx.x * 256 + threadIdx.x;
    if (i < n4) {
        float4 v = ((const float4*)x)[i];
        ushort4 o;
        o.x = f2bf(v.x); o.y = f2bf(v.y); o.z = f2bf(v.z); o.w = f2bf(v.w);
        ((ushort4*)y)[i] = o;
    }
}

// ---------------------------------------------------------------------------
// Transpose-cast: W [512 x 512] (k-major rows) -> WT [512 x 512] bf16, WT[n][k]
// ---------------------------------------------------------------------------
__global__ __launch_bounds__(256) void transpose_cast(
    const float* __restrict__ W, unsigned short* __restrict__ WT)
{
    __shared__ float tile[32][33];
    const int tx = threadIdx.x;          // 0..31
    const int ty = threadIdx.y;          // 0..7
    const int k0 = blockIdx.y * 32, n0 = blockIdx.x * 32;
    #pragma unroll
    for (int i = 0; i < 32; i += 8)
        tile[ty + i][tx] = W[(size_t)(k0 + ty + i) * KDIM + n0 + tx];
    __syncthreads();
    #pragma unroll
    for (int i = 0; i < 32; i += 8)
        WT[(size_t)(n0 + ty + i) * KDIM + k0 + tx] = f2bf(tile[tx][ty + i]);
}

// ---------------------------------------------------------------------------
// Staged NT MFMA core (m97-ladder structure): block computes 128x128 f32 tile
// of A[M,K] @ B[N,K]^T. 256 threads / 4 waves, each wave a 64x64 subtile.
// Per BK=32 k-step: stage A,B 128x32 bf16 tiles into LDS via
// global_load_lds (16B/lane, 2 issues per operand), barrier, 8 ds_read_b128
// fragment loads + 16 MFMA per wave, barrier.
// LDS row = 32 bf16 = 64 B; lane l of wave wv stages row wv*16 + l/4,
// byte col (l%4)*16 — matches the base+lane*16 DMA rule.
// ---------------------------------------------------------------------------
template<int KSTEPS>
__device__ __forceinline__ void mfma_nt_staged(
    const unsigned short* __restrict__ A, const unsigned short* __restrict__ B,
    int lda, int ldb, int bm, int bn,
    unsigned short* AsLDS, unsigned short* BsLDS, f32x4 acc[4][4])
{
    const int t = threadIdx.x;
    const int wv = t >> 6, ln = t & 63;
    const int r = ln & 15, quad = ln >> 4;
    const int wm = (wv >> 1) * 64, wn = (wv & 1) * 64;
    const int srow = wv * 16 + (ln >> 2);     // staging row (+ j*64)
    const int scol = (ln & 3) * 8;            // staging col in bf16 elems (16 B)

    for (int ks = 0; ks < KSTEPS; ++ks) {
        const int k0 = ks * 32;
        #pragma unroll
        for (int j = 0; j < 2; ++j) {
            gload_lds16(A + (size_t)(bm + j * 64 + srow) * lda + k0 + scol,
                        AsLDS + (size_t)(j * 64 + wv * 16) * 32);
            gload_lds16(B + (size_t)(bn + j * 64 + srow) * ldb + k0 + scol,
                        BsLDS + (size_t)(j * 64 + wv * 16) * 32);
        }
        __syncthreads();   // drains vmcnt (DMA) + lgkm, then barrier
        bf16x8 af[4], bg[4];
        #pragma unroll
        for (int f = 0; f < 4; ++f)
            af[f] = *(const bf16x8*)(AsLDS + (size_t)(wm + f * 16 + r) * 32 + quad * 8);
        #pragma unroll
        for (int f = 0; f < 4; ++f)
            bg[f] = *(const bf16x8*)(BsLDS + (size_t)(wn + f * 16 + r) * 32 + quad * 8);
        #pragma unroll
        for (int i = 0; i < 4; ++i)
            #pragma unroll
            for (int j2 = 0; j2 < 4; ++j2)
                acc[i][j2] = __builtin_amdgcn_mfma_f32_16x16x32_bf16(
                    af[i], bg[j2], acc[i][j2], 0, 0, 0);
        __syncthreads();   // protect LDS before next-stage overwrite
    }
}

__device__ __forceinline__ void zero_acc(f32x4 acc[4][4]) {
    #pragma unroll
    for (int i = 0; i < 4; ++i)
        #pragma unroll
        for (int j = 0; j < 4; ++j)
            acc[i][j] = f32x4{0.f, 0.f, 0.f, 0.f};
}

// ---------------------------------------------------------------------------
// Projection: C[M x 1024] bf16 = A[M x 512] @ WT[1024 x 512]^T + bias
// grid (1024/128, M/128)
// ---------------------------------------------------------------------------
__global__ __launch_bounds__(256) void proj_mfma(
    const unsigned short* __restrict__ A, const unsigned short* __restrict__ WT,
    const float* __restrict__ bias_m, const float* __restrict__ bias_c,
    unsigned short* __restrict__ C)
{
    __shared__ unsigned short As[128 * 32];
    __shared__ unsigned short Bs[128 * 32];
    const int bm = blockIdx.y * 128, bn = blockIdx.x * 128;
    f32x4 acc[4][4]; zero_acc(acc);
    mfma_nt_staged<16>(A, WT, KDIM, KDIM, bm, bn, As, Bs, acc);
    const int wv = threadIdx.x >> 6, ln = threadIdx.x & 63;
    const int r = ln & 15, quad = ln >> 4;
    const int m0 = bm + (wv >> 1) * 64, n0 = bn + (wv & 1) * 64;
    #pragma unroll
    for (int j = 0; j < 4; ++j) {
        const int n = n0 + j * 16 + r;
        const float bv = (n < 512) ? bias_m[n] : bias_c[n - 512];
        #pragma unroll
        for (int i = 0; i < 4; ++i) {
            #pragma unroll
            for (int reg = 0; reg < 4; ++reg) {
                const int m = m0 + i * 16 + quad * 4 + reg;
                C[(size_t)m * 1024 + n] = f2bf(acc[i][j][reg] + bv);
            }
        }
    }
}

// ---------------------------------------------------------------------------
// p_choose: per batch b, p = sigmoid(qm[b] @ km[b]^T / sqrt(512) + r + noise)
// grid (2048/128, 256/128, 8)
// ---------------------------------------------------------------------------
__global__ __launch_bounds__(256) void pchoose_mfma(
    const unsigned short* __restrict__ qp, const unsigned short* __restrict__ kp,
    const float* __restrict__ noise, const float* __restrict__ rp,
    float* __restrict__ p)
{
    __shared__ unsigned short As[128 * 32];
    __shared__ unsigned short Bs[128 * 32];
    const int b = blockIdx.z;
    const unsigned short* A = qp + (size_t)b * QLEN * 1024;
    const unsigned short* B = kp + (size_t)b * KLEN * 1024;
    const int bm = blockIdx.y * 128, bn = blockIdx.x * 128;
    f32x4 acc[4][4]; zero_acc(acc);
    mfma_nt_staged<16>(A, B, 1024, 1024, bm, bn, As, Bs, acc);
    const int wv = threadIdx.x >> 6, ln = threadIdx.x & 63;
    const int r = ln & 15, quad = ln >> 4;
    const int m0 = bm + (wv >> 1) * 64, n0 = bn + (wv & 1) * 64;
    const float rv = rp[0];
    #pragma unroll
    for (int i = 0; i < 4; ++i) {
        #pragma unroll
        for (int reg = 0; reg < 4; ++reg) {
            const int q = m0 + i * 16 + quad * 4 + reg;
            const size_t rowoff = ((size_t)b * QLEN + q) * KLEN;
            #pragma unroll
            for (int j = 0; j < 4; ++j) {
                const int k = n0 + j * 16 + r;
                const float e = acc[i][j][reg] * INV_SCALE + rv + noise[rowoff + k];
                p[rowoff + k] = __builtin_amdgcn_rcpf(1.0f + __expf(-e));
            }
        }
    }
}

// ---------------------------------------------------------------------------
// e_chunk: per (b,h), out[b,h,q,k] = qc_h[b] @ kc_h[b]^T / sqrt(512)
// grid (2048/128, 256/128, 32); K=128 -> 4 staged k-steps
// ---------------------------------------------------------------------------
__global__ __launch_bounds__(256) void echunk_mfma(
    const unsigned short* __restrict__ qp, const unsigned short* __restrict__ kp,
    float* __restrict__ out)
{
    __shared__ unsigned short As[128 * 32];
    __shared__ unsigned short Bs[128 * 32];
    const int z = blockIdx.z, b = z >> 2, h = z & 3;
    const unsigned short* A = qp + (size_t)b * QLEN * 1024 + 512 + h * DKH;
    const unsigned short* B = kp + (size_t)b * KLEN * 1024 + 512 + h * DKH;
    const int bm = blockIdx.y * 128, bn = blockIdx.x * 128;
    f32x4 acc[4][4]; zero_acc(acc);
    mfma_nt_staged<4>(A, B, 1024, 1024, bm, bn, As, Bs, acc);
    const int wv = threadIdx.x >> 6, ln = threadIdx.x & 63;
    const int r = ln & 15, quad = ln >> 4;
    const int m0 = bm + (wv >> 1) * 64, n0 = bn + (wv & 1) * 64;
    #pragma unroll
    for (int i = 0; i < 4; ++i) {
        #pragma unroll
        for (int reg = 0; reg < 4; ++reg) {
            const int q = m0 + i * 16 + quad * 4 + reg;
            const size_t rowoff = (((size_t)z) * QLEN + q) * KLEN;
            #pragma unroll
            for (int j = 0; j < 4; ++j) {
                const int k = n0 + j * 16 + r;
                out[rowoff + k] = acc[i][j][reg] * INV_SCALE;
            }
        }
    }
}

// ---------------------------------------------------------------------------
// 64-lane inclusive prefix sum via DPP (≈6 VALU ops, no LDS round-trips)
// ---------------------------------------------------------------------------
__device__ __forceinline__ float wave_incl_scan(float x)
{
#define DPP_ADD(ctrl, rmask, bctrl)                                            \
    { int _t = __builtin_amdgcn_update_dpp(0, __builtin_bit_cast(int, x),      \
                                           ctrl, rmask, 0xf, bctrl);           \
      x += __builtin_bit_cast(float, _t); }
    DPP_ADD(0x111, 0xf, true)   // row_shr:1
    DPP_ADD(0x112, 0xf, true)   // row_shr:2
    DPP_ADD(0x114, 0xf, true)   // row_shr:4
    DPP_ADD(0x118, 0xf, true)   // row_shr:8
    DPP_ADD(0x142, 0xa, false)  // row_bcast:15 -> rows 1,3
    DPP_ADD(0x143, 0xc, false)  // row_bcast:31 -> rows 2,3
#undef DPP_ADD
    return x;
}

// ---------------------------------------------------------------------------
// cumprod_mr: per (b,q) row (2048 independent blocks, fully parallel):
//   cp = exp(exclusive_cumsum(log(clip(1-p,1e-6,1))))
//   m  = p * cp ;  r = 1/clip(cp,1e-6,1)
// Fast intrinsics; absorbs ALL transcendental work off the serial scan.
// ---------------------------------------------------------------------------
__global__ __launch_bounds__(256) void cumprod_mr(
    const float* __restrict__ p, float* __restrict__ mArr, float* __restrict__ rArr)
{
    const size_t row = blockIdx.x;
    const float* pr = p + row * KLEN;
    float* mr = mArr + row * KLEN;
    float* rr = rArr + row * KLEN;
    const int tid = threadIdx.x;
    const int lane = tid & 63, wid = tid >> 6;
    __shared__ float waveTot[4];

    float4 v0 = *(const float4*)(pr + tid * 8);
    float4 v1 = *(const float4*)(pr + tid * 8 + 4);
    float pv[8] = {v0.x, v0.y, v0.z, v0.w, v1.x, v1.y, v1.z, v1.w};
    float excl[8];
    float run = 0.0f;
    #pragma unroll
    for (int j = 0; j < 8; ++j) {
        float l = __logf(fminf(fmaxf(1.0f - pv[j], EPSV), 1.0f));
        excl[j] = run;
        run += l;
    }
    float s = wave_incl_scan(run);
    if (lane == 63) waveTot[wid] = s;
    __syncthreads();
    float wex = 0.0f;
    for (int w = 0; w < wid; ++w) wex += waveTot[w];
    const float texcl = wex + s - run;

    float mv[8], rv[8];
    #pragma unroll
    for (int j = 0; j < 8; ++j) {
        const float cpv = __expf(texcl + excl[j]);
        mv[j] = pv[j] * cpv;
        rv[j] = __builtin_amdgcn_rcpf(fminf(fmaxf(cpv, EPSV), 1.0f));
    }
    *(float4*)(mr + tid * 8)     = *(float4*)&mv[0];
    *(float4*)(mr + tid * 8 + 4) = *(float4*)&mv[4];
    *(float4*)(rr + tid * 8)     = *(float4*)&rv[0];
    *(float4*)(rr + tid * 8 + 4) = *(float4*)&rv[4];
}

// ---------------------------------------------------------------------------
// alpha_scan: pure recurrence over q, m/r precomputed. 1 block/batch,
// 512 threads (8 waves), 4 contiguous k per lane. ~45 VALU instrs/step.
// ---------------------------------------------------------------------------
__global__ __launch_bounds__(512, 1) void alpha_scan(
    const float* __restrict__ mArr, const float* __restrict__ rArr,
    float* __restrict__ alpha)
{
    const int b = blockIdx.x;
    const int tid = threadIdx.x;               // 0..511
    const int lane = tid & 63, wid = tid >> 6; // 8 waves
    __shared__ __align__(16) float wt[2][8];

    const float* mrow = mArr + (size_t)b * QLEN * KLEN + tid * 4;
    const float* rrow = rArr + (size_t)b * QLEN * KLEN + tid * 4;
    float* arow = alpha + (size_t)b * QLEN * KLEN + tid * 4;

    float aw0 = 0.f, aw1 = 0.f, aw2 = 0.f, aw3 = 0.f;
    if (tid == 0) aw0 = 1.0f;   // aw_prev one-hot at k=0

    float4 mA = *(const float4*)(mrow);
    float4 rA = *(const float4*)(rrow);
    float4 mB = *(const float4*)(mrow + KLEN);
    float4 rB = *(const float4*)(rrow + KLEN);

#define ASTEP(I, MREG, RREG)                                                   \
    {                                                                          \
        const int i_ = (I);                                                    \
        float4 mc = MREG, rc = RREG;                                           \
        const int rn_ = (i_ + 2 < QLEN) ? (i_ + 2) : (QLEN - 1);               \
        MREG = *(const float4*)(mrow + (size_t)rn_ * KLEN);                    \
        RREG = *(const float4*)(rrow + (size_t)rn_ * KLEN);                    \
        float run = 0.0f, i0, i1, i2, i3;                                      \
        run = fmaf(aw0, rc.x, run); i0 = run;                                  \
        run = fmaf(aw1, rc.y, run); i1 = run;                                  \
        run = fmaf(aw2, rc.z, run); i2 = run;                                  \
        run = fmaf(aw3, rc.w, run); i3 = run;                                  \
        float tot = wave_incl_scan(run);                                       \
        if (lane == 63) wt[i_ & 1][wid] = tot;                                 \
        lds_barrier();                                                         \
        float base = tot - run;                                                \
        float4 w0 = *(const float4*)&wt[i_ & 1][0];                            \
        float4 w1 = *(const float4*)&wt[i_ & 1][4];                            \
        if (wid > 0) base += w0.x;                                             \
        if (wid > 1) base += w0.y;                                             \
        if (wid > 2) base += w0.z;                                             \
        if (wid > 3) base += w0.w;                                             \
        if (wid > 4) base += w1.x;                                             \
        if (wid > 5) base += w1.y;                                             \
        if (wid > 6) base += w1.z;                                             \
        aw0 = mc.x * (base + i0);                                              \
        aw1 = mc.y * (base + i1);                                              \
        aw2 = mc.z * (base + i2);                                              \
        aw3 = mc.w * (base + i3);                                              \
        float4 ov; ov.x = aw0; ov.y = aw1; ov.z = aw2; ov.w = aw3;             \
        *(float4*)(arow + (size_t)i_ * KLEN) = ov;                             \
    }

    for (int io = 0; io < QLEN; io += 2) {
        ASTEP(io + 0, mA, rA)
        ASTEP(io + 1, mB, rB)
    }
#undef ASTEP
}

// ---------------------------------------------------------------------------
// beta: per (b,h,q) row of 2048 (e_chunk in d_out, overwritten)
// ---------------------------------------------------------------------------
__global__ __launch_bounds__(256) void beta_kernel(
    float* __restrict__ eo, const float* __restrict__ alpha)
{
    __shared__ float sse[KLEN + 3];
    __shared__ float su[KLEN + 3];
    __shared__ float wmax[4];

    const int tid = threadIdx.x;
    const int lane = tid & 63, wid = tid >> 6;
    const int row = blockIdx.x;                 // [B*H*Q]
    const int q = row & (QLEN - 1);
    const int b = row >> 10;
    float* erow = eo + (size_t)row * KLEN;
    const float* arow = alpha + ((size_t)b * QLEN + q) * KLEN;

    if (tid < 3) { sse[tid] = 0.0f; su[KLEN + tid] = 0.0f; }

    float ev[8];
    float lm = -INFINITY;
    #pragma unroll
    for (int j = 0; j < 8; ++j) {
        const int k = tid + 256 * j;
        ev[j] = erow[k];
        lm = fmaxf(lm, ev[j]);
    }
    #pragma unroll
    for (int off = 32; off > 0; off >>= 1) lm = fmaxf(lm, __shfl_xor(lm, off));
    if (lane == 0) wmax[wid] = lm;
    __syncthreads();
    const float mx = fmaxf(fmaxf(wmax[0], wmax[1]), fmaxf(wmax[2], wmax[3]));

    #pragma unroll
    for (int j = 0; j < 8; ++j) {
        const int k = tid + 256 * j;
        sse[k + 3] = fmaxf(__expf(ev[j] - mx), 1e-5f);
    }
    __syncthreads();

    #pragma unroll
    for (int j = 0; j < 8; ++j) {
        const int k = tid + 256 * j;
        const float denom = sse[k + 3] + sse[k + 2] + sse[k + 1] + sse[k];
        su[k] = arow[k] * __builtin_amdgcn_rcpf(denom);
    }
    __syncthreads();

    #pragma unroll
    for (int j = 0; j < 8; ++j) {
        const int k = tid + 256 * j;
        erow[k] = sse[k + 3] * (su[k] + su[k + 1] + su[k + 2] + su[k + 3]);
    }
}

// ---------------------------------------------------------------------------
extern "C" void kernel_launch(void* const* d_in, const int* in_sizes, int n_in,
                              void* d_out, int out_size, void* d_ws, size_t ws_size,
                              hipStream_t stream)
{
    (void)in_sizes; (void)n_in; (void)out_size; (void)ws_size;
    const float* key_enc = (const float*)d_in[0];   // [8,2048,512]
    const float* query   = (const float*)d_in[1];   // [8,256,512]
    const float* noise   = (const float*)d_in[2];   // [8,256,2048]
    const float* Wk_m    = (const float*)d_in[3];
    const float* bk_m    = (const float*)d_in[4];
    const float* Wq_m    = (const float*)d_in[5];
    const float* bq_m    = (const float*)d_in[6];
    const float* rp      = (const float*)d_in[7];
    const float* Wk_c    = (const float*)d_in[8];
    const float* bk_c    = (const float*)d_in[9];
    const float* Wq_c    = (const float*)d_in[10];
    const float* bq_c    = (const float*)d_in[11];
    float* out = (float*)d_out;                     // [8,4,256,2048]

    // workspace layout (bytes)
    char* w = (char*)d_ws;
    unsigned short* kx    = (unsigned short*)w; w += (size_t)BATCH * KLEN * KDIM * 2;   // 16.8 MB
    unsigned short* qx    = (unsigned short*)w; w += (size_t)BATCH * QLEN * KDIM * 2;   //  2.1 MB
    unsigned short* WTk   = (unsigned short*)w; w += (size_t)1024 * KDIM * 2;           //  1.0 MB
    unsigned short* WTq   = (unsigned short*)w; w += (size_t)1024 * KDIM * 2;           //  1.0 MB
    unsigned short* kproj = (unsigned short*)w; w += (size_t)BATCH * KLEN * 1024 * 2;   // 33.6 MB
    unsigned short* qproj = (unsigned short*)w; w += (size_t)BATCH * QLEN * 1024 * 2;   //  4.2 MB
    float* p_alpha = (float*)w; w += (size_t)BATCH * QLEN * KLEN * 4;                   // 16.8 MB
    float* mArr    = (float*)w; w += (size_t)BATCH * QLEN * KLEN * 4;                   // 16.8 MB
    float* rArr    = (float*)w;                                                         // 16.8 MB

    // 1) casts
    hipLaunchKernelGGL(cast_bf16, dim3(BATCH * KLEN * KDIM / 4 / 256), dim3(256), 0, stream,
                       key_enc, kx, BATCH * KLEN * KDIM / 4);
    hipLaunchKernelGGL(cast_bf16, dim3(BATCH * QLEN * KDIM / 4 / 256), dim3(256), 0, stream,
                       query, qx, BATCH * QLEN * KDIM / 4);
    hipLaunchKernelGGL(transpose_cast, dim3(16, 16), dim3(32, 8), 0, stream, Wk_m, WTk);
    hipLaunchKernelGGL(transpose_cast, dim3(16, 16), dim3(32, 8), 0, stream, Wk_c, WTk + (size_t)512 * KDIM);
    hipLaunchKernelGGL(transpose_cast, dim3(16, 16), dim3(32, 8), 0, stream, Wq_m, WTq);
    hipLaunchKernelGGL(transpose_cast, dim3(16, 16), dim3(32, 8), 0, stream, Wq_c, WTq + (size_t)512 * KDIM);

    // 2) projections (staged bf16 MFMA, fused bias, bf16 out)
    hipLaunchKernelGGL(proj_mfma, dim3(8, BATCH * KLEN / 128), dim3(256), 0, stream,
                       kx, WTk, bk_m, bk_c, kproj);
    hipLaunchKernelGGL(proj_mfma, dim3(8, BATCH * QLEN / 128), dim3(256), 0, stream,
                       qx, WTq, bq_m, bq_c, qproj);

    // 3) p_choose (staged bf16 MFMA + fast sigmoid epilogue)
    hipLaunchKernelGGL(pchoose_mfma, dim3(KLEN / 128, QLEN / 128, BATCH), dim3(256), 0, stream,
                       qproj, kproj, noise, rp, p_alpha);

    // 4) cumprod -> (m, r)  (parallel, absorbs all transcendentals)
    hipLaunchKernelGGL(cumprod_mr, dim3(BATCH * QLEN), dim3(256), 0, stream,
                       p_alpha, mArr, rArr);

    // 5) alpha recurrence (serial, lean) — writes over dead p buffer
    hipLaunchKernelGGL(alpha_scan, dim3(BATCH), dim3(512), 0, stream,
                       mArr, rArr, p_alpha);

    // 6) e_chunk (staged bf16 MFMA) into d_out
    hipLaunchKernelGGL(echunk_mfma, dim3(KLEN / 128, QLEN / 128, BATCH * NHEADS), dim3(256), 0, stream,
                       qproj, kproj, out);

    // 7) beta (overwrites e_chunk rows in d_out)
    hipLaunchKernelGGL(beta_kernel, dim3(BATCH * NHEADS * QLEN), dim3(256), 0, stream,
                       out, p_alpha);
}